// Round 10
// baseline (427.848 us; speedup 1.0000x reference)
//
#include <hip/hip_runtime.h>
#include <hip/hip_fp16.h>

// SDConv on MI355X.
// Reference: out = sum_k spmm(L_k, X) @ W_k + bias  (complex).
// Structure: apply W AFTER the spmm (k-expansion lives in the L domain), so the
// gather table is just X: 25.6 MB fp16 -> L2/L3-resident.
//   1. prep_kernel: Xh[node][ch] = half2(Xr,Xi); epay[e] = 32 B pre-swizzled edge
//      record {col,(lr,-li)k,(li,lr)k} written COALESCED in edge order; zero counts.
//   2. CSR build: histogram -> scan -> pos_kernel scatters only perm[pos]=e
//      (4 B/edge random write into 6.4 MB -> L2/L3-absorbed churn).
//   3. row4_kernel: one wave per row; wave-uniform CSR walk (scalar pipe):
//      perm[p] (+4 ahead) -> epay[perm] (+3) -> Xh gather (+2); 6 dot2/edge.
//      Writes Y planar f16.
//   4. yw2_kernel: out = sum_k Y_k @ W_k + bias as packed-pair dot2 GEMM, f32 acc.

constexpr int N_NODES = 100000;
constexpr int E_EDGES = 1600000;
constexpr int CH = 64;
constexpr int NP = 100096;          // N padded to multiple of 256
constexpr int NBLK = NP / 256;      // 391

typedef unsigned u32x2 __attribute__((ext_vector_type(2)));
typedef _Float16 h2f __attribute__((ext_vector_type(2)));

// f32 += dot(half2, half2) with f32 accumulation (v_dot2_f32_f16).
__device__ __forceinline__ float fdot2h(unsigned a, unsigned b, float c) {
#if __has_builtin(__builtin_amdgcn_fdot2)
    return __builtin_amdgcn_fdot2(__builtin_bit_cast(h2f, a),
                                  __builtin_bit_cast(h2f, b), c, false);
#else
    float2 af = __half22float2(__builtin_bit_cast(__half2, a));
    float2 bf = __half22float2(__builtin_bit_cast(__half2, b));
    return c + af.x * bf.x + af.y * bf.y;
#endif
}

__device__ __forceinline__ unsigned pack2(float a, float b) {
    return __builtin_bit_cast(unsigned, __floats2half2_rn(a, b));
}

__global__ __launch_bounds__(256) void init_out_kernel(const float* __restrict__ bias,
                                                       float* __restrict__ out) {
    int i = blockIdx.x * 256 + threadIdx.x;
    out[i] = bias[i & 63];
}

// ---------------- Phase 1: Xh pack + epay build (coalesced) + zero counts ----------------
// grid = 6250 x 256 = 1.6M threads: thread i does Xh float4-item i AND edge i.
__global__ __launch_bounds__(256) void prep_kernel(const float* __restrict__ Xr,
                                                   const float* __restrict__ Xi,
                                                   const int* __restrict__ cols,
                                                   const float* __restrict__ Lr,
                                                   const float* __restrict__ Li,
                                                   unsigned* __restrict__ Xh,
                                                   uint4* __restrict__ epay,
                                                   int* __restrict__ counts) {
    int i = blockIdx.x * 256 + threadIdx.x;
    if (i < NP) counts[i] = 0;

    // Xh: N*64/4 = 1.6M float4 items, exact.
    const float4 r = ((const float4*)Xr)[i];
    const float4 m = ((const float4*)Xi)[i];
    uint4 u;
    u.x = pack2(r.x, m.x);
    u.y = pack2(r.y, m.y);
    u.z = pack2(r.z, m.z);
    u.w = pack2(r.w, m.w);
    ((uint4*)Xh)[i] = u;

    // epay: pre-swizzled 32 B record in EDGE order (coalesced write).
    const float lr0 = Lr[i], li0 = Li[i];
    const float lr1 = Lr[E_EDGES + i], li1 = Li[E_EDGES + i];
    const float lr2 = Lr[2 * E_EDGES + i], li2 = Li[2 * E_EDGES + i];
    uint4 e0, e1;
    e0.x = (unsigned)cols[i];
    e0.y = pack2(lr0, -li0);
    e0.z = pack2(li0, lr0);
    e0.w = pack2(lr1, -li1);
    e1.x = pack2(li1, lr1);
    e1.y = pack2(lr2, -li2);
    e1.z = pack2(li2, lr2);
    e1.w = 0u;
    epay[2 * (size_t)i] = e0;
    epay[2 * (size_t)i + 1] = e1;
}

// ---------------- CSR build ----------------
__global__ __launch_bounds__(256) void hist_kernel(const int* __restrict__ rows,
                                                   int* __restrict__ counts) {
    int e = blockIdx.x * 256 + threadIdx.x;
    if (e < E_EDGES) atomicAdd(&counts[rows[e]], 1);
}

__global__ __launch_bounds__(256) void scan_a_kernel(const int* __restrict__ counts,
                                                     int* __restrict__ rowst,
                                                     int* __restrict__ btot) {
    __shared__ int s[256];
    const int t = threadIdx.x;
    const int g = blockIdx.x * 256 + t;
    int v = counts[g];
    s[t] = v;
    __syncthreads();
    for (int off = 1; off < 256; off <<= 1) {
        int a = (t >= off) ? s[t - off] : 0;
        __syncthreads();
        s[t] += a;
        __syncthreads();
    }
    rowst[g] = s[t] - v;
    if (t == 255) btot[blockIdx.x] = s[255];
}

__global__ __launch_bounds__(512) void scan_b_kernel(int* __restrict__ btot) {
    __shared__ int s[512];
    const int t = threadIdx.x;
    int v = (t < NBLK) ? btot[t] : 0;
    s[t] = v;
    __syncthreads();
    for (int off = 1; off < 512; off <<= 1) {
        int a = (t >= off) ? s[t - off] : 0;
        __syncthreads();
        s[t] += a;
        __syncthreads();
    }
    if (t < NBLK) btot[t] = s[t] - v;
}

__global__ __launch_bounds__(256) void scan_c_kernel(const int* __restrict__ btot,
                                                     int* __restrict__ rowst,
                                                     int* __restrict__ cursor) {
    const int g = blockIdx.x * 256 + threadIdx.x;
    int v = rowst[g] + btot[blockIdx.x];
    rowst[g] = v;
    cursor[g] = v;
}

// Only a 4 B edge-id goes to the random position: churn fits in L2/L3.
__global__ __launch_bounds__(256) void pos_kernel(const int* __restrict__ rows,
                                                  int* __restrict__ cursor,
                                                  int* __restrict__ perm) {
    int e = blockIdx.x * 256 + threadIdx.x;
    if (e >= E_EDGES) return;
    int pos = atomicAdd(&cursor[rows[e]], 1);
    perm[pos] = e;
}

// ---------------- Main pass: one wave per row, scalar perm->epay chain + dot2 ----------------
__global__ __launch_bounds__(256) void row4_kernel(const int* __restrict__ rowst,
                                                   const int* __restrict__ perm,
                                                   const uint4* __restrict__ epay,
                                                   const unsigned* __restrict__ Xh,
                                                   __half* __restrict__ Yre,
                                                   __half* __restrict__ Yim) {
    // Wave-uniform row index -> perm/epay addresses provably uniform -> scalar pipe.
    const int r = __builtin_amdgcn_readfirstlane(blockIdx.x * 4 + ((int)threadIdx.x >> 6));
    const int lane = threadIdx.x & 63;
    if (r >= N_NODES) return;
    const int start = rowst[r];
    const int end = rowst[r + 1];
    const int n = end - start;

    float aR0 = 0.f, aI0 = 0.f, aR1 = 0.f, aI1 = 0.f, aR2 = 0.f, aI2 = 0.f;

    auto gx = [&](unsigned col) -> unsigned { return Xh[(size_t)col * 64 + lane]; };
    auto accum = [&](const uint4& q0, const uint4& q1, unsigned xv) {
        aR0 = fdot2h(q0.y, xv, aR0);
        aI0 = fdot2h(q0.z, xv, aI0);
        aR1 = fdot2h(q0.w, xv, aR1);
        aI1 = fdot2h(q1.x, xv, aI1);
        aR2 = fdot2h(q1.y, xv, aR2);
        aI2 = fdot2h(q1.z, xv, aI2);
    };

    if (n > 0) {
        int p = start;
        uint4 z;
        z.x = z.y = z.z = z.w = 0u;
        uint4 a0, a1, b0 = z, b1 = z, c0 = z, c1 = z;
        unsigned xB = 0u;
        int pmD = 0;

        const int pmA = perm[p];
        a0 = epay[2 * (size_t)pmA];
        a1 = epay[2 * (size_t)pmA + 1];
        unsigned xA = gx(a0.x);
        if (n > 1) {
            const int pmB = perm[p + 1];
            b0 = epay[2 * (size_t)pmB];
            b1 = epay[2 * (size_t)pmB + 1];
            xB = gx(b0.x);
        }
        if (n > 2) {
            const int pmC = perm[p + 2];
            c0 = epay[2 * (size_t)pmC];
            c1 = epay[2 * (size_t)pmC + 1];
        }
        if (n > 3) pmD = perm[p + 3];

        for (; p + 4 < end; ++p) {
            const int pmE = perm[p + 4];                    // scalar, +4 ahead
            uint4 d0 = epay[2 * (size_t)pmD];               // scalar 32 B, +3 ahead
            uint4 d1 = epay[2 * (size_t)pmD + 1];
            unsigned xC = gx(c0.x);                         // vector gather, +2 ahead
            accum(a0, a1, xA);
            a0 = b0; a1 = b1; xA = xB;
            b0 = c0; b1 = c1; xB = xC;
            c0 = d0; c1 = d1;
            pmD = pmE;
        }
        // remaining min(n,4) edges: a(ready), b(ready), c(no x yet), pmD(no epay yet)
        accum(a0, a1, xA);
        if (p + 1 < end) accum(b0, b1, xB);
        if (p + 2 < end) {
            unsigned xC = gx(c0.x);
            accum(c0, c1, xC);
        }
        if (p + 3 < end) {
            uint4 d0 = epay[2 * (size_t)pmD];
            uint4 d1 = epay[2 * (size_t)pmD + 1];
            unsigned xD = gx(d0.x);
            accum(d0, d1, xD);
        }
    }

    __half* yr = Yre + (size_t)r * 192;
    __half* yi = Yim + (size_t)r * 192;
    yr[lane] = __float2half(aR0);
    yr[64 + lane] = __float2half(aR1);
    yr[128 + lane] = __float2half(aR2);
    yi[lane] = __float2half(aI0);
    yi[64 + lane] = __float2half(aI1);
    yi[128 + lane] = __float2half(aI2);
}

// ---------------- Phase 4: out = Y @ Wcat + bias via packed-pair dot2 ----------------
// Yre/Yim: [N][192] f16 (t = k*64 + j). Wcat: [192][64] f32 (row-major [3][64][64]).
__global__ __launch_bounds__(256) void yw2_kernel(const __half* __restrict__ Yre,
                                                  const __half* __restrict__ Yim,
                                                  const float* __restrict__ W,
                                                  const float* __restrict__ bias,
                                                  float* __restrict__ out) {
    __shared__ unsigned sW2[96][64];     // [t-pair][col] = half2(W[2t][c], W[2t+1][c])  24 KB
    __shared__ unsigned sY[2][32][96];   // [re/im][row][t-pair]                          24 KB
    const int tid = threadIdx.x;

    for (int idx = tid; idx < 96 * 64; idx += 256) {
        const int kp = idx >> 6, c = idx & 63;
        sW2[kp][c] = pack2(W[(2 * kp) * 64 + c], W[(2 * kp + 1) * 64 + c]);
    }

    const int rowbase = blockIdx.x * 32;                 // grid = N/32 = 3125 exact
    const uint4* gYr = (const uint4*)(Yre + (size_t)rowbase * 192);
    const uint4* gYi = (const uint4*)(Yim + (size_t)rowbase * 192);
    uint4* sYr4 = (uint4*)&sY[0][0][0];
    uint4* sYi4 = (uint4*)&sY[1][0][0];
    for (int i = tid; i < 768; i += 256) {
        sYr4[i] = gYr[i];
        sYi4[i] = gYi[i];
    }
    __syncthreads();

    const int col = tid & 63;
    const int rg = tid >> 6;
    const float b = bias[col];

    float accR[8], accI[8];
#pragma unroll
    for (int i = 0; i < 8; ++i) { accR[i] = 0.f; accI[i] = 0.f; }

#pragma unroll 4
    for (int kpp = 0; kpp < 48; ++kpp) {
        const unsigned w0 = sW2[2 * kpp][col];       // stride-1 across lanes: conflict-free
        const unsigned w1 = sW2[2 * kpp + 1][col];
#pragma unroll
        for (int i = 0; i < 8; ++i) {
            const int row = rg * 8 + i;
            u32x2 yr = *(const u32x2*)&sY[0][row][2 * kpp];   // uniform addr -> broadcast
            u32x2 yi = *(const u32x2*)&sY[1][row][2 * kpp];
            accR[i] = fdot2h(yr.x, w0, accR[i]);
            accR[i] = fdot2h(yr.y, w1, accR[i]);
            accI[i] = fdot2h(yi.x, w0, accI[i]);
            accI[i] = fdot2h(yi.y, w1, accI[i]);
        }
    }

#pragma unroll
    for (int i = 0; i < 8; ++i) {
        const int row = rowbase + rg * 8 + i;
        __builtin_nontemporal_store(accR[i] + b, &out[(size_t)row * 64 + col]);
        __builtin_nontemporal_store(accI[i] + b, &out[(size_t)(N_NODES + row) * 64 + col]);
    }
}

// ================= Fallback kernels (small-ws paths) =================
template <int NK>
__global__ __launch_bounds__(256) void xw_kernel(const float* __restrict__ Xr,
                                                 const float* __restrict__ Xi,
                                                 const float* __restrict__ W,
                                                 __half2* __restrict__ XWh) {
    __shared__ float sW[NK][64][64];
    __shared__ float4 sX4[2][32][16];
    const int tid = threadIdx.x;

    float4* swf = (float4*)&sW[0][0][0];
    const float4* gW = (const float4*)W;
    for (int i = tid; i < NK * 1024; i += 256) swf[i] = gW[i];

    const int rowbase = blockIdx.x * 32;
    float4* sxf = (float4*)sX4;
    const float4* gXr = (const float4*)(Xr + (size_t)rowbase * CH);
    const float4* gXi = (const float4*)(Xi + (size_t)rowbase * CH);
    for (int i = tid; i < 512; i += 256) {
        sxf[i] = gXr[i];
        sxf[512 + i] = gXi[i];
    }
    __syncthreads();

    const int col = tid & 63;
    const int rg = tid >> 6;

    float acc[8][2 * NK];
#pragma unroll
    for (int i = 0; i < 8; ++i)
#pragma unroll
        for (int c2 = 0; c2 < 2 * NK; ++c2) acc[i][c2] = 0.0f;

#pragma unroll 2
    for (int j4 = 0; j4 < 16; ++j4) {
        float w[NK][4];
#pragma unroll
        for (int k = 0; k < NK; ++k)
#pragma unroll
            for (int jj = 0; jj < 4; ++jj) w[k][jj] = sW[k][j4 * 4 + jj][col];
#pragma unroll
        for (int i = 0; i < 8; ++i) {
            float4 xr = sX4[0][rg * 8 + i][j4];
            float4 xi = sX4[1][rg * 8 + i][j4];
            const float xra[4] = {xr.x, xr.y, xr.z, xr.w};
            const float xia[4] = {xi.x, xi.y, xi.z, xi.w};
#pragma unroll
            for (int jj = 0; jj < 4; ++jj)
#pragma unroll
                for (int k = 0; k < NK; ++k) {
                    acc[i][2 * k] += xra[jj] * w[k][jj];
                    acc[i][2 * k + 1] += xia[jj] * w[k][jj];
                }
        }
    }

#pragma unroll
    for (int i = 0; i < 8; ++i) {
        __half2* dst = XWh + (size_t)(rowbase + rg * 8 + i) * (NK * 64);
#pragma unroll
        for (int k = 0; k < NK; ++k)
            dst[k * 64 + col] = __floats2half2_rn(acc[i][2 * k], acc[i][2 * k + 1]);
    }
}

template <int NK>
__global__ __launch_bounds__(256) void edge_kernel(const int* __restrict__ rows,
                                                   const int* __restrict__ cols,
                                                   const float* __restrict__ Lr,
                                                   const float* __restrict__ Li,
                                                   const __half2* __restrict__ XWh,
                                                   float* __restrict__ out) {
    const int gid = blockIdx.x * 256 + threadIdx.x;
    const int e = gid >> 6;
    const int lane = gid & 63;
    if (e >= E_EDGES) return;

    const int row = rows[e];
    const int colN = cols[e];
    const __half2* xw = XWh + (size_t)colN * (NK * 64);

    float rc = 0.0f, ic = 0.0f;
#pragma unroll
    for (int k = 0; k < NK; ++k) {
        const float lr = Lr[(size_t)k * E_EDGES + e];
        const float li = Li[(size_t)k * E_EDGES + e];
        float2 v = __half22float2(xw[k * 64 + lane]);
        rc += lr * v.x - li * v.y;
        ic += li * v.x + lr * v.y;
    }
    unsafeAtomicAdd(out + (size_t)row * 64 + lane, rc);
    unsafeAtomicAdd(out + ((size_t)N_NODES + row) * 64 + lane, ic);
}

extern "C" void kernel_launch(void* const* d_in, const int* in_sizes, int n_in,
                              void* d_out, int out_size, void* d_ws, size_t ws_size,
                              hipStream_t stream) {
    const float* Xr = (const float*)d_in[0];
    const float* Xi = (const float*)d_in[1];
    const int* ei = (const int*)d_in[2];
    const float* Lr = (const float*)d_in[3];
    const float* Li = (const float*)d_in[4];
    const float* W = (const float*)d_in[5];
    const float* bias = (const float*)d_in[6];
    float* out = (float*)d_out;

    const int* rows = ei;
    const int* cols = ei + E_EDGES;

    char* wsb = (char*)d_ws;
    const int e_grid = E_EDGES / 256;                             // 6250
    const int edge_grid = (int)((size_t)E_EDGES * 64 / 256);      // 400000
    const int gemm_grid = N_NODES / 32;                           // 3125

    // Main-path ws layout
    unsigned* Xh = (unsigned*)wsb;                                //  25,600,000 B
    __half* Yre = (__half*)(wsb + 25600000);                      //  38,400,000 B
    __half* Yim = (__half*)(wsb + 64000000);                      //  38,400,000 B
    uint4* epay = (uint4*)(wsb + 102400000);                      //  51,200,000 B (32 B/edge)
    int* perm = (int*)(wsb + 153600000);                          //   6,400,000 B
    int* counts = (int*)(wsb + 160000000);                        //     400,384 B
    int* rowst = (int*)(wsb + 160400384);                         //     400,384 B
    int* cursor = (int*)(wsb + 160800768);                        //     400,384 B
    int* btot = (int*)(wsb + 161201152);                          //       2,048 B
    const size_t need_new = 161203200;

    if (ws_size >= need_new) {
        prep_kernel<<<6250, 256, 0, stream>>>(Xr, Xi, cols, Lr, Li, Xh, epay, counts);
        hist_kernel<<<e_grid, 256, 0, stream>>>(rows, counts);
        scan_a_kernel<<<NBLK, 256, 0, stream>>>(counts, rowst, btot);
        scan_b_kernel<<<1, 512, 0, stream>>>(btot);
        scan_c_kernel<<<NBLK, 256, 0, stream>>>(btot, rowst, cursor);
        pos_kernel<<<e_grid, 256, 0, stream>>>(rows, cursor, perm);
        row4_kernel<<<(N_NODES + 3) / 4, 256, 0, stream>>>(rowst, perm, epay, Xh, Yre, Yim);
        yw2_kernel<<<gemm_grid, 256, 0, stream>>>(Yre, Yim, W, bias, out);
        return;
    }

    // Fallback ws layout (atomic edge scatter over XWh table)
    __half2* XWh = (__half2*)wsb;                                 //  76,800,000 B
    const size_t need_onepass = 76800000;

    if (ws_size >= need_onepass) {
        init_out_kernel<<<2 * N_NODES * CH / 256, 256, 0, stream>>>(bias, out);
        xw_kernel<3><<<gemm_grid, 256, 0, stream>>>(Xr, Xi, W, XWh);
        edge_kernel<3><<<edge_grid, 256, 0, stream>>>(rows, cols, Lr, Li, XWh, out);
    } else {
        init_out_kernel<<<2 * N_NODES * CH / 256, 256, 0, stream>>>(bias, out);
        for (int k = 0; k < 3; ++k) {
            xw_kernel<1><<<gemm_grid, 256, 0, stream>>>(Xr, Xi, W + (size_t)k * 4096, XWh);
            edge_kernel<1><<<edge_grid, 256, 0, stream>>>(rows, cols,
                                                          Lr + (size_t)k * E_EDGES,
                                                          Li + (size_t)k * E_EDGES, XWh, out);
        }
    }
}

// Round 11
// 338.107 us; speedup vs baseline: 1.2654x; 1.2654x over previous
//
#include <hip/hip_runtime.h>
#include <hip/hip_fp16.h>

// SDConv on MI355X.
// Reference: out = sum_k spmm(L_k, X) @ W_k + bias  (complex).
// Structure: apply W AFTER the spmm (k-expansion lives in the L domain), so the
// gather table is just X: 25.6 MB fp16 -> L2/L3-resident.
//   1. xh_zero_kernel: Xh[node][ch] = half2(Xr, Xi); also zeros hist counters.
//   2. CSR build: histogram -> scan -> payload scatter (32 B/edge, PRE-SWIZZLED
//      L pairs {col,(lr,-li)k,(li,lr)k}), NON-TEMPORAL stores (random 64B-line
//      writeback amplification measured in R9/R10: every random store = 64B wb).
//   3. row3_kernel: one wave per row; wave-uniform payload walk (scalar pipe);
//      depth-3 payload / depth-2 gather pipeline; 6x v_dot2_f32_f16 per edge.
//      Writes Y planar f16: Yre[n][192], Yim[n][192].
//   4. yw3_kernel: out = [Yre;Yim] @ W + bias via v_mfma_f32_16x16x32_f16
//      (M=2x100K tall-skinny GEMM, memory-floor ~22 us).

constexpr int N_NODES = 100000;
constexpr int E_EDGES = 1600000;
constexpr int CH = 64;
constexpr int NP = 100096;          // N padded to multiple of 256
constexpr int NBLK = NP / 256;      // 391

typedef unsigned u32x2 __attribute__((ext_vector_type(2)));
typedef unsigned u32x4 __attribute__((ext_vector_type(4)));
typedef _Float16 h2f __attribute__((ext_vector_type(2)));
typedef _Float16 h8f __attribute__((ext_vector_type(8)));
typedef float f32x4 __attribute__((ext_vector_type(4)));

// f32 += dot(half2, half2) with f32 accumulation (v_dot2_f32_f16).
__device__ __forceinline__ float fdot2h(unsigned a, unsigned b, float c) {
#if __has_builtin(__builtin_amdgcn_fdot2)
    return __builtin_amdgcn_fdot2(__builtin_bit_cast(h2f, a),
                                  __builtin_bit_cast(h2f, b), c, false);
#else
    float2 af = __half22float2(__builtin_bit_cast(__half2, a));
    float2 bf = __half22float2(__builtin_bit_cast(__half2, b));
    return c + af.x * bf.x + af.y * bf.y;
#endif
}

__device__ __forceinline__ unsigned pack2(float a, float b) {
    return __builtin_bit_cast(unsigned, __floats2half2_rn(a, b));
}

__global__ __launch_bounds__(256) void init_out_kernel(const float* __restrict__ bias,
                                                       float* __restrict__ out) {
    int i = blockIdx.x * 256 + threadIdx.x;
    out[i] = bias[i & 63];
}

// ---------------- Phase 1: Xh = half2(Xr, Xi), [N][64]; zero hist counts ----------------
__global__ __launch_bounds__(256) void xh_zero_kernel(const float* __restrict__ Xr,
                                                      const float* __restrict__ Xi,
                                                      unsigned* __restrict__ Xh,
                                                      int* __restrict__ counts) {
    int i = blockIdx.x * 256 + threadIdx.x;   // grid = N*64/4/256 = 6250 exact
    if (i < NP) counts[i] = 0;
    const float4 r = ((const float4*)Xr)[i];
    const float4 m = ((const float4*)Xi)[i];
    uint4 u;
    u.x = pack2(r.x, m.x);
    u.y = pack2(r.y, m.y);
    u.z = pack2(r.z, m.z);
    u.w = pack2(r.w, m.w);
    ((uint4*)Xh)[i] = u;
}

// ---------------- CSR build ----------------
__global__ __launch_bounds__(256) void hist_kernel(const int* __restrict__ rows,
                                                   int* __restrict__ counts) {
    int e = blockIdx.x * 256 + threadIdx.x;
    if (e < E_EDGES) atomicAdd(&counts[rows[e]], 1);
}

__global__ __launch_bounds__(256) void scan_a_kernel(const int* __restrict__ counts,
                                                     int* __restrict__ rowst,
                                                     int* __restrict__ btot) {
    __shared__ int s[256];
    const int t = threadIdx.x;
    const int g = blockIdx.x * 256 + t;
    int v = counts[g];
    s[t] = v;
    __syncthreads();
    for (int off = 1; off < 256; off <<= 1) {
        int a = (t >= off) ? s[t - off] : 0;
        __syncthreads();
        s[t] += a;
        __syncthreads();
    }
    rowst[g] = s[t] - v;
    if (t == 255) btot[blockIdx.x] = s[255];
}

__global__ __launch_bounds__(512) void scan_b_kernel(int* __restrict__ btot) {
    __shared__ int s[512];
    const int t = threadIdx.x;
    int v = (t < NBLK) ? btot[t] : 0;
    s[t] = v;
    __syncthreads();
    for (int off = 1; off < 512; off <<= 1) {
        int a = (t >= off) ? s[t - off] : 0;
        __syncthreads();
        s[t] += a;
        __syncthreads();
    }
    if (t < NBLK) btot[t] = s[t] - v;
}

__global__ __launch_bounds__(256) void scan_c_kernel(const int* __restrict__ btot,
                                                     int* __restrict__ rowst,
                                                     int* __restrict__ cursor) {
    const int g = blockIdx.x * 256 + threadIdx.x;
    int v = rowst[g] + btot[blockIdx.x];
    rowst[g] = v;
    cursor[g] = v;
}

// payload per edge (32 B): {col, (lr0,-li0), (li0,lr0), (lr1,-li1)} {(li1,lr1), (lr2,-li2), (li2,lr2), 0}
__global__ __launch_bounds__(256) void scatter_kernel(const int* __restrict__ rows,
                                                      const int* __restrict__ cols,
                                                      const float* __restrict__ Lr,
                                                      const float* __restrict__ Li,
                                                      int* __restrict__ cursor,
                                                      unsigned* __restrict__ payload) {
    int e = blockIdx.x * 256 + threadIdx.x;
    if (e >= E_EDGES) return;
    int r = rows[e];
    int pos = atomicAdd(&cursor[r], 1);
    const float lr0 = Lr[e], li0 = Li[e];
    const float lr1 = Lr[E_EDGES + e], li1 = Li[E_EDGES + e];
    const float lr2 = Lr[2 * E_EDGES + e], li2 = Li[2 * E_EDGES + e];
    u32x4 u0, u1;
    u0.x = (unsigned)cols[e];
    u0.y = pack2(lr0, -li0);
    u0.z = pack2(li0, lr0);
    u0.w = pack2(lr1, -li1);
    u1.x = pack2(li1, lr1);
    u1.y = pack2(lr2, -li2);
    u1.z = pack2(li2, lr2);
    u1.w = 0u;
    // Non-temporal: avoid 64B-line RFO/writeback amplification on random scatter.
    u32x4* dst = (u32x4*)(payload + 8 * (size_t)pos);
    __builtin_nontemporal_store(u0, dst);
    __builtin_nontemporal_store(u1, dst + 1);
}

// ---------------- Main pass: one wave per row, scalar payload + dot2 ----------------
__global__ __launch_bounds__(256) void row3_kernel(const int* __restrict__ rowst,
                                                   const uint4* __restrict__ payload,
                                                   const unsigned* __restrict__ Xh,
                                                   __half* __restrict__ Yre,
                                                   __half* __restrict__ Yim) {
    // Wave-uniform row index: payload addresses provably uniform -> scalar pipe.
    const int r = __builtin_amdgcn_readfirstlane(blockIdx.x * 4 + ((int)threadIdx.x >> 6));
    const int lane = threadIdx.x & 63;
    if (r >= N_NODES) return;
    const int start = rowst[r];
    const int end = rowst[r + 1];
    const int n = end - start;

    float aR0 = 0.f, aI0 = 0.f, aR1 = 0.f, aI1 = 0.f, aR2 = 0.f, aI2 = 0.f;

    auto gx = [&](unsigned col) -> unsigned { return Xh[(size_t)col * 64 + lane]; };
    auto accum = [&](const uint4& q0, const uint4& q1, unsigned xv) {
        aR0 = fdot2h(q0.y, xv, aR0);
        aI0 = fdot2h(q0.z, xv, aI0);
        aR1 = fdot2h(q0.w, xv, aR1);
        aI1 = fdot2h(q1.x, xv, aI1);
        aR2 = fdot2h(q1.y, xv, aR2);
        aI2 = fdot2h(q1.z, xv, aI2);
    };

    if (n > 0) {
        int p = start;
        uint4 a0 = payload[2 * (size_t)p], a1 = payload[2 * (size_t)p + 1];
        unsigned xA = gx(a0.x);
        uint4 b0, b1, c0, c1;
        b0.x = b0.y = b0.z = b0.w = 0u;
        b1 = b0; c0 = b0; c1 = b0;
        unsigned xB = 0u;
        if (n > 1) {
            b0 = payload[2 * (size_t)(p + 1)];
            b1 = payload[2 * (size_t)(p + 1) + 1];
            xB = gx(b0.x);
        }
        if (n > 2) {
            c0 = payload[2 * (size_t)(p + 2)];
            c1 = payload[2 * (size_t)(p + 2) + 1];
        }
        for (; p + 3 < end; ++p) {
            unsigned xC = gx(c0.x);                       // gather for p+2: 2 iters of slack
            uint4 d0 = payload[2 * (size_t)(p + 3)];      // payload for p+3 (scalar pipe)
            uint4 d1 = payload[2 * (size_t)(p + 3) + 1];
            accum(a0, a1, xA);
            a0 = b0; a1 = b1; xA = xB;
            b0 = c0; b1 = c1; xB = xC;
            c0 = d0; c1 = d1;
        }
        // rem = end - p in {1,2,3}
        accum(a0, a1, xA);
        if (p + 1 < end) accum(b0, b1, xB);
        if (p + 2 < end) {
            unsigned xC = gx(c0.x);
            accum(c0, c1, xC);
        }
    }

    __half* yr = Yre + (size_t)r * 192;
    __half* yi = Yim + (size_t)r * 192;
    yr[lane] = __float2half(aR0);
    yr[64 + lane] = __float2half(aR1);
    yr[128 + lane] = __float2half(aR2);
    yi[lane] = __float2half(aI0);
    yi[64 + lane] = __float2half(aI1);
    yi[128 + lane] = __float2half(aI2);
}

// ---------------- Phase 4: out = [Yre;Yim] @ Wcat + bias via MFMA ----------------
// Yre/Yim: [N][192] f16. W: [192][64] f32 flat. 16x16x32 f16 MFMA.
// A frag: row = lane&15, k = (lane>>4)*8 + j (8 contiguous halves).
// B frag: col = lane&15, k = (lane>>4)*8 + j.
// D frag: col = lane&15, row = (lane>>4)*4 + r.
__global__ __launch_bounds__(256) void yw3_kernel(const __half* __restrict__ Yre,
                                                  const __half* __restrict__ Yim,
                                                  const float* __restrict__ W,
                                                  const float* __restrict__ bias,
                                                  float* __restrict__ out) {
    __shared__ h8f sB[24][64];   // [(kc*4)+nt][lane-pattern] pre-packed B frags, 24 KB
    const int tid = threadIdx.x;

    for (int s = tid; s < 24 * 64; s += 256) {
        const int L = s & 63;
        const int ntkc = s >> 6;           // 0..23
        const int nt = ntkc & 3;
        const int kc = ntkc >> 2;
        const int colb = nt * 16 + (L & 15);
        const int kbase = kc * 32 + ((L >> 4) << 3);
        h8f v;
#pragma unroll
        for (int j = 0; j < 8; ++j) v[j] = (_Float16)W[(kbase + j) * 64 + colb];
        sB[ntkc][L] = v;
    }
    __syncthreads();

    const int wv = tid >> 6;
    const int L = tid & 63;
    const int band = blockIdx.x * 64 + wv * 16;     // grid = 1563, tail waves exit
    if (band >= N_NODES) return;

    const int m = L & 15;
    const int ko = (L >> 4) << 3;
    const int rowA = band + m;                      // band+15 <= 99999 always (100000%16==0)

    f32x4 accR[4], accI[4];
#pragma unroll
    for (int nt = 0; nt < 4; ++nt) {
        accR[nt] = (f32x4){0.f, 0.f, 0.f, 0.f};
        accI[nt] = (f32x4){0.f, 0.f, 0.f, 0.f};
    }

#pragma unroll
    for (int kc = 0; kc < 6; ++kc) {
        h8f aR = *(const h8f*)(Yre + (size_t)rowA * 192 + kc * 32 + ko);
        h8f aI = *(const h8f*)(Yim + (size_t)rowA * 192 + kc * 32 + ko);
#pragma unroll
        for (int nt = 0; nt < 4; ++nt) {
            h8f bf = sB[kc * 4 + nt][L];
            accR[nt] = __builtin_amdgcn_mfma_f32_16x16x32_f16(aR, bf, accR[nt], 0, 0, 0);
            accI[nt] = __builtin_amdgcn_mfma_f32_16x16x32_f16(aI, bf, accI[nt], 0, 0, 0);
        }
    }

    const int colw = L & 15;
    const int rbase = (L >> 4) << 2;
#pragma unroll
    for (int nt = 0; nt < 4; ++nt) {
        const float b = bias[nt * 16 + colw];
#pragma unroll
        for (int rr = 0; rr < 4; ++rr) {
            const int row = band + rbase + rr;
            __builtin_nontemporal_store(accR[nt][rr] + b,
                                        &out[(size_t)row * 64 + nt * 16 + colw]);
            __builtin_nontemporal_store(accI[nt][rr] + b,
                                        &out[(size_t)(N_NODES + row) * 64 + nt * 16 + colw]);
        }
    }
}

// ================= Fallback kernels (small-ws paths) =================
template <int NK>
__global__ __launch_bounds__(256) void xw_kernel(const float* __restrict__ Xr,
                                                 const float* __restrict__ Xi,
                                                 const float* __restrict__ W,
                                                 __half2* __restrict__ XWh) {
    __shared__ float sW[NK][64][64];
    __shared__ float4 sX4[2][32][16];
    const int tid = threadIdx.x;

    float4* swf = (float4*)&sW[0][0][0];
    const float4* gW = (const float4*)W;
    for (int i = tid; i < NK * 1024; i += 256) swf[i] = gW[i];

    const int rowbase = blockIdx.x * 32;
    float4* sxf = (float4*)sX4;
    const float4* gXr = (const float4*)(Xr + (size_t)rowbase * CH);
    const float4* gXi = (const float4*)(Xi + (size_t)rowbase * CH);
    for (int i = tid; i < 512; i += 256) {
        sxf[i] = gXr[i];
        sxf[512 + i] = gXi[i];
    }
    __syncthreads();

    const int col = tid & 63;
    const int rg = tid >> 6;

    float acc[8][2 * NK];
#pragma unroll
    for (int i = 0; i < 8; ++i)
#pragma unroll
        for (int c2 = 0; c2 < 2 * NK; ++c2) acc[i][c2] = 0.0f;

#pragma unroll 2
    for (int j4 = 0; j4 < 16; ++j4) {
        float w[NK][4];
#pragma unroll
        for (int k = 0; k < NK; ++k)
#pragma unroll
            for (int jj = 0; jj < 4; ++jj) w[k][jj] = sW[k][j4 * 4 + jj][col];
#pragma unroll
        for (int i = 0; i < 8; ++i) {
            float4 xr = sX4[0][rg * 8 + i][j4];
            float4 xi = sX4[1][rg * 8 + i][j4];
            const float xra[4] = {xr.x, xr.y, xr.z, xr.w};
            const float xia[4] = {xi.x, xi.y, xi.z, xi.w};
#pragma unroll
            for (int jj = 0; jj < 4; ++jj)
#pragma unroll
                for (int k = 0; k < NK; ++k) {
                    acc[i][2 * k] += xra[jj] * w[k][jj];
                    acc[i][2 * k + 1] += xia[jj] * w[k][jj];
                }
        }
    }

#pragma unroll
    for (int i = 0; i < 8; ++i) {
        __half2* dst = XWh + (size_t)(rowbase + rg * 8 + i) * (NK * 64);
#pragma unroll
        for (int k = 0; k < NK; ++k)
            dst[k * 64 + col] = __floats2half2_rn(acc[i][2 * k], acc[i][2 * k + 1]);
    }
}

template <int NK>
__global__ __launch_bounds__(256) void edge_kernel(const int* __restrict__ rows,
                                                   const int* __restrict__ cols,
                                                   const float* __restrict__ Lr,
                                                   const float* __restrict__ Li,
                                                   const __half2* __restrict__ XWh,
                                                   float* __restrict__ out) {
    const int gid = blockIdx.x * 256 + threadIdx.x;
    const int e = gid >> 6;
    const int lane = gid & 63;
    if (e >= E_EDGES) return;

    const int row = rows[e];
    const int colN = cols[e];
    const __half2* xw = XWh + (size_t)colN * (NK * 64);

    float rc = 0.0f, ic = 0.0f;
#pragma unroll
    for (int k = 0; k < NK; ++k) {
        const float lr = Lr[(size_t)k * E_EDGES + e];
        const float li = Li[(size_t)k * E_EDGES + e];
        float2 v = __half22float2(xw[k * 64 + lane]);
        rc += lr * v.x - li * v.y;
        ic += li * v.x + lr * v.y;
    }
    unsafeAtomicAdd(out + (size_t)row * 64 + lane, rc);
    unsafeAtomicAdd(out + ((size_t)N_NODES + row) * 64 + lane, ic);
}

extern "C" void kernel_launch(void* const* d_in, const int* in_sizes, int n_in,
                              void* d_out, int out_size, void* d_ws, size_t ws_size,
                              hipStream_t stream) {
    const float* Xr = (const float*)d_in[0];
    const float* Xi = (const float*)d_in[1];
    const int* ei = (const int*)d_in[2];
    const float* Lr = (const float*)d_in[3];
    const float* Li = (const float*)d_in[4];
    const float* W = (const float*)d_in[5];
    const float* bias = (const float*)d_in[6];
    float* out = (float*)d_out;

    const int* rows = ei;
    const int* cols = ei + E_EDGES;

    char* wsb = (char*)d_ws;
    const int e_grid = E_EDGES / 256;                             // 6250
    const int edge_grid = (int)((size_t)E_EDGES * 64 / 256);      // 400000
    const int gemm_grid = N_NODES / 32;                           // 3125

    // Main-path ws layout
    unsigned* Xh = (unsigned*)wsb;                                //  25,600,000 B
    __half* Yre = (__half*)(wsb + 25600000);                      //  38,400,000 B
    __half* Yim = (__half*)(wsb + 64000000);                      //  38,400,000 B
    unsigned* payload = (unsigned*)(wsb + 102400000);             //  51,200,000 B (32 B/edge)
    int* counts = (int*)(wsb + 153600000);                        //     400,384 B
    int* rowst = (int*)(wsb + 154000384);                         //     400,384 B
    int* cursor = (int*)(wsb + 154400768);                        //     400,384 B
    int* btot = (int*)(wsb + 154801152);                          //       2,048 B
    const size_t need_new = 154803200;

    if (ws_size >= need_new) {
        xh_zero_kernel<<<6250, 256, 0, stream>>>(Xr, Xi, Xh, counts);
        hist_kernel<<<e_grid, 256, 0, stream>>>(rows, counts);
        scan_a_kernel<<<NBLK, 256, 0, stream>>>(counts, rowst, btot);
        scan_b_kernel<<<1, 512, 0, stream>>>(btot);
        scan_c_kernel<<<NBLK, 256, 0, stream>>>(btot, rowst, cursor);
        scatter_kernel<<<e_grid, 256, 0, stream>>>(rows, cols, Lr, Li, cursor, payload);
        row3_kernel<<<(N_NODES + 3) / 4, 256, 0, stream>>>(rowst, (const uint4*)payload,
                                                           Xh, Yre, Yim);
        yw3_kernel<<<(N_NODES + 63) / 64, 256, 0, stream>>>(Yre, Yim, W, bias, out);
        return;
    }

    // Fallback ws layout (atomic edge scatter over XWh table)
    __half2* XWh = (__half2*)wsb;                                 //  76,800,000 B
    const size_t need_onepass = 76800000;

    if (ws_size >= need_onepass) {
        init_out_kernel<<<2 * N_NODES * CH / 256, 256, 0, stream>>>(bias, out);
        xw_kernel<3><<<gemm_grid, 256, 0, stream>>>(Xr, Xi, W, XWh);
        edge_kernel<3><<<edge_grid, 256, 0, stream>>>(rows, cols, Lr, Li, XWh, out);
    } else {
        init_out_kernel<<<2 * N_NODES * CH / 256, 256, 0, stream>>>(bias, out);
        for (int k = 0; k < 3; ++k) {
            xw_kernel<1><<<gemm_grid, 256, 0, stream>>>(Xr, Xi, W + (size_t)k * 4096, XWh);
            edge_kernel<1><<<edge_grid, 256, 0, stream>>>(rows, cols,
                                                          Lr + (size_t)k * E_EDGES,
                                                          Li + (size_t)k * E_EDGES, XWh, out);
        }
    }
}

// Round 12
// 314.757 us; speedup vs baseline: 1.3593x; 1.0742x over previous
//
#include <hip/hip_runtime.h>
#include <hip/hip_fp16.h>

// SDConv on MI355X.
// Reference: out = sum_k spmm(L_k, X) @ W_k + bias  (complex).
// Structure: apply W AFTER the spmm (k-expansion lives in the L domain), so the
// gather table is just X: 25.6 MB fp16 -> L2/L3-resident.
//   1. xh_zero_kernel: Xh[node][ch] = half2(Xr, Xi); also zeros hist counters.
//   2. CSR build: histogram -> scan -> payload scatter (32 B/edge, PRE-SWIZZLED
//      L pairs {col,(lr,-li)k,(li,lr)k}), NON-TEMPORAL stores.
//   3. row5_kernel: one wave per row; wave-uniform payload walk (scalar pipe);
//      2 edges/iter, 6-slot payload pipeline, 4 gathers in flight; 6 dot2/edge.
//      Writes Y planar f16: Yre[n][192], Yim[n][192].
//   4. yw3_kernel: out = [Yre;Yim] @ W + bias via v_mfma_f32_16x16x32_f16.

constexpr int N_NODES = 100000;
constexpr int E_EDGES = 1600000;
constexpr int CH = 64;
constexpr int NP = 100096;          // N padded to multiple of 256
constexpr int NBLK = NP / 256;      // 391

typedef unsigned u32x4 __attribute__((ext_vector_type(4)));
typedef _Float16 h2f __attribute__((ext_vector_type(2)));
typedef _Float16 h8f __attribute__((ext_vector_type(8)));
typedef float f32x4 __attribute__((ext_vector_type(4)));

// f32 += dot(half2, half2) with f32 accumulation (v_dot2_f32_f16).
__device__ __forceinline__ float fdot2h(unsigned a, unsigned b, float c) {
#if __has_builtin(__builtin_amdgcn_fdot2)
    return __builtin_amdgcn_fdot2(__builtin_bit_cast(h2f, a),
                                  __builtin_bit_cast(h2f, b), c, false);
#else
    float2 af = __half22float2(__builtin_bit_cast(__half2, a));
    float2 bf = __half22float2(__builtin_bit_cast(__half2, b));
    return c + af.x * bf.x + af.y * bf.y;
#endif
}

__device__ __forceinline__ unsigned pack2(float a, float b) {
    return __builtin_bit_cast(unsigned, __floats2half2_rn(a, b));
}

__global__ __launch_bounds__(256) void init_out_kernel(const float* __restrict__ bias,
                                                       float* __restrict__ out) {
    int i = blockIdx.x * 256 + threadIdx.x;
    out[i] = bias[i & 63];
}

// ---------------- Phase 1: Xh = half2(Xr, Xi), [N][64]; zero hist counts ----------------
__global__ __launch_bounds__(256) void xh_zero_kernel(const float* __restrict__ Xr,
                                                      const float* __restrict__ Xi,
                                                      unsigned* __restrict__ Xh,
                                                      int* __restrict__ counts) {
    int i = blockIdx.x * 256 + threadIdx.x;   // grid = N*64/4/256 = 6250 exact
    if (i < NP) counts[i] = 0;
    const float4 r = ((const float4*)Xr)[i];
    const float4 m = ((const float4*)Xi)[i];
    uint4 u;
    u.x = pack2(r.x, m.x);
    u.y = pack2(r.y, m.y);
    u.z = pack2(r.z, m.z);
    u.w = pack2(r.w, m.w);
    ((uint4*)Xh)[i] = u;
}

// ---------------- CSR build ----------------
__global__ __launch_bounds__(256) void hist_kernel(const int* __restrict__ rows,
                                                   int* __restrict__ counts) {
    int e = blockIdx.x * 256 + threadIdx.x;
    if (e < E_EDGES) atomicAdd(&counts[rows[e]], 1);
}

__global__ __launch_bounds__(256) void scan_a_kernel(const int* __restrict__ counts,
                                                     int* __restrict__ rowst,
                                                     int* __restrict__ btot) {
    __shared__ int s[256];
    const int t = threadIdx.x;
    const int g = blockIdx.x * 256 + t;
    int v = counts[g];
    s[t] = v;
    __syncthreads();
    for (int off = 1; off < 256; off <<= 1) {
        int a = (t >= off) ? s[t - off] : 0;
        __syncthreads();
        s[t] += a;
        __syncthreads();
    }
    rowst[g] = s[t] - v;
    if (t == 255) btot[blockIdx.x] = s[255];
}

__global__ __launch_bounds__(512) void scan_b_kernel(int* __restrict__ btot) {
    __shared__ int s[512];
    const int t = threadIdx.x;
    int v = (t < NBLK) ? btot[t] : 0;
    s[t] = v;
    __syncthreads();
    for (int off = 1; off < 512; off <<= 1) {
        int a = (t >= off) ? s[t - off] : 0;
        __syncthreads();
        s[t] += a;
        __syncthreads();
    }
    if (t < NBLK) btot[t] = s[t] - v;
}

__global__ __launch_bounds__(256) void scan_c_kernel(const int* __restrict__ btot,
                                                     int* __restrict__ rowst,
                                                     int* __restrict__ cursor) {
    const int g = blockIdx.x * 256 + threadIdx.x;
    int v = rowst[g] + btot[blockIdx.x];
    rowst[g] = v;
    cursor[g] = v;
}

// payload per edge (32 B): {col, (lr0,-li0), (li0,lr0), (lr1,-li1)} {(li1,lr1), (lr2,-li2), (li2,lr2), 0}
__global__ __launch_bounds__(256) void scatter_kernel(const int* __restrict__ rows,
                                                      const int* __restrict__ cols,
                                                      const float* __restrict__ Lr,
                                                      const float* __restrict__ Li,
                                                      int* __restrict__ cursor,
                                                      unsigned* __restrict__ payload) {
    int e = blockIdx.x * 256 + threadIdx.x;
    if (e >= E_EDGES) return;
    int r = rows[e];
    int pos = atomicAdd(&cursor[r], 1);
    const float lr0 = Lr[e], li0 = Li[e];
    const float lr1 = Lr[E_EDGES + e], li1 = Li[E_EDGES + e];
    const float lr2 = Lr[2 * E_EDGES + e], li2 = Li[2 * E_EDGES + e];
    u32x4 u0, u1;
    u0.x = (unsigned)cols[e];
    u0.y = pack2(lr0, -li0);
    u0.z = pack2(li0, lr0);
    u0.w = pack2(lr1, -li1);
    u1.x = pack2(li1, lr1);
    u1.y = pack2(lr2, -li2);
    u1.z = pack2(li2, lr2);
    u1.w = 0u;
    // Non-temporal: avoid 64B-line RFO/writeback amplification on random scatter.
    u32x4* dst = (u32x4*)(payload + 8 * (size_t)pos);
    __builtin_nontemporal_store(u0, dst);
    __builtin_nontemporal_store(u1, dst + 1);
}

// ---------------- Main pass: one wave per row, 2 edges/iter, 4 gathers in flight ----------------
__global__ __launch_bounds__(256) void row5_kernel(const int* __restrict__ rowst,
                                                   const uint4* __restrict__ payload,
                                                   const unsigned* __restrict__ Xh,
                                                   __half* __restrict__ Yre,
                                                   __half* __restrict__ Yim) {
    // Wave-uniform row index: payload addresses provably uniform -> scalar pipe.
    const int r = __builtin_amdgcn_readfirstlane(blockIdx.x * 4 + ((int)threadIdx.x >> 6));
    const int lane = threadIdx.x & 63;
    if (r >= N_NODES) return;
    const int start = rowst[r];
    const int end = rowst[r + 1];
    const int n = end - start;

    float aR0 = 0.f, aI0 = 0.f, aR1 = 0.f, aI1 = 0.f, aR2 = 0.f, aI2 = 0.f;

    auto gx = [&](unsigned col) -> unsigned { return Xh[(size_t)col * 64 + lane]; };
    auto accum = [&](const uint4& q0, const uint4& q1, unsigned xv) {
        aR0 = fdot2h(q0.y, xv, aR0);
        aI0 = fdot2h(q0.z, xv, aI0);
        aR1 = fdot2h(q0.w, xv, aR1);
        aI1 = fdot2h(q1.x, xv, aI1);
        aR2 = fdot2h(q1.y, xv, aR2);
        aI2 = fdot2h(q1.z, xv, aI2);
    };

    if (n >= 8) {
        int p = start;
        // Prologue: payload slots A..F = p..p+5; gathers for A..D in flight.
        uint4 A0 = payload[2 * (size_t)p], A1 = payload[2 * (size_t)p + 1];
        uint4 B0 = payload[2 * (size_t)(p + 1)], B1 = payload[2 * (size_t)(p + 1) + 1];
        uint4 C0 = payload[2 * (size_t)(p + 2)], C1 = payload[2 * (size_t)(p + 2) + 1];
        uint4 D0 = payload[2 * (size_t)(p + 3)], D1 = payload[2 * (size_t)(p + 3) + 1];
        uint4 E0 = payload[2 * (size_t)(p + 4)], E1 = payload[2 * (size_t)(p + 4) + 1];
        uint4 F0 = payload[2 * (size_t)(p + 5)], F1 = payload[2 * (size_t)(p + 5) + 1];
        unsigned xA = gx(A0.x), xB = gx(B0.x), xC = gx(C0.x), xD = gx(D0.x);

        for (; p + 7 < end; p += 2) {
            uint4 G0 = payload[2 * (size_t)(p + 6)], G1 = payload[2 * (size_t)(p + 6) + 1];
            uint4 H0 = payload[2 * (size_t)(p + 7)], H1 = payload[2 * (size_t)(p + 7) + 1];
            unsigned xE = gx(E0.x);
            unsigned xF = gx(F0.x);
            accum(A0, A1, xA);
            accum(B0, B1, xB);
            A0 = C0; A1 = C1; xA = xC;
            B0 = D0; B1 = D1; xB = xD;
            C0 = E0; C1 = E1; xC = xE;
            D0 = F0; D1 = F1; xD = xF;
            E0 = G0; E1 = G1;
            F0 = H0; F1 = H1;
        }
        // Exit: rem = end - p in {6, 7}. A..D have gathers ready; E,F payload-only.
        accum(A0, A1, xA);
        accum(B0, B1, xB);
        accum(C0, C1, xC);
        accum(D0, D1, xD);
        unsigned xE = gx(E0.x);
        unsigned xF = gx(F0.x);
        accum(E0, E1, xE);
        accum(F0, F1, xF);
        if (p + 6 < end) {
            uint4 G0 = payload[2 * (size_t)(p + 6)], G1 = payload[2 * (size_t)(p + 6) + 1];
            unsigned xG = gx(G0.x);
            accum(G0, G1, xG);
        }
    } else {
        // Rare (~1% of rows at avg degree 16): simple serial walk.
        for (int p = start; p < end; ++p) {
            uint4 q0 = payload[2 * (size_t)p], q1 = payload[2 * (size_t)p + 1];
            unsigned xv = gx(q0.x);
            accum(q0, q1, xv);
        }
    }

    __half* yr = Yre + (size_t)r * 192;
    __half* yi = Yim + (size_t)r * 192;
    yr[lane] = __float2half(aR0);
    yr[64 + lane] = __float2half(aR1);
    yr[128 + lane] = __float2half(aR2);
    yi[lane] = __float2half(aI0);
    yi[64 + lane] = __float2half(aI1);
    yi[128 + lane] = __float2half(aI2);
}

// ---------------- Phase 4: out = [Yre;Yim] @ Wcat + bias via MFMA ----------------
// Yre/Yim: [N][192] f16. W: [192][64] f32 flat. 16x16x32 f16 MFMA.
// A frag: row = lane&15, k = (lane>>4)*8 + j (8 contiguous halves).
// B frag: col = lane&15, k = (lane>>4)*8 + j.
// D frag: col = lane&15, row = (lane>>4)*4 + r.
__global__ __launch_bounds__(256) void yw3_kernel(const __half* __restrict__ Yre,
                                                  const __half* __restrict__ Yim,
                                                  const float* __restrict__ W,
                                                  const float* __restrict__ bias,
                                                  float* __restrict__ out) {
    __shared__ h8f sB[24][64];   // [(kc*4)+nt][lane-pattern] pre-packed B frags, 24 KB
    const int tid = threadIdx.x;

    for (int s = tid; s < 24 * 64; s += 256) {
        const int L = s & 63;
        const int ntkc = s >> 6;           // 0..23
        const int nt = ntkc & 3;
        const int kc = ntkc >> 2;
        const int colb = nt * 16 + (L & 15);
        const int kbase = kc * 32 + ((L >> 4) << 3);
        h8f v;
#pragma unroll
        for (int j = 0; j < 8; ++j) v[j] = (_Float16)W[(kbase + j) * 64 + colb];
        sB[ntkc][L] = v;
    }
    __syncthreads();

    const int wv = tid >> 6;
    const int L = tid & 63;
    const int band = blockIdx.x * 64 + wv * 16;     // grid = 1563, tail waves exit
    if (band >= N_NODES) return;

    const int m = L & 15;
    const int ko = (L >> 4) << 3;
    const int rowA = band + m;

    f32x4 accR[4], accI[4];
#pragma unroll
    for (int nt = 0; nt < 4; ++nt) {
        accR[nt] = (f32x4){0.f, 0.f, 0.f, 0.f};
        accI[nt] = (f32x4){0.f, 0.f, 0.f, 0.f};
    }

#pragma unroll
    for (int kc = 0; kc < 6; ++kc) {
        h8f aR = *(const h8f*)(Yre + (size_t)rowA * 192 + kc * 32 + ko);
        h8f aI = *(const h8f*)(Yim + (size_t)rowA * 192 + kc * 32 + ko);
#pragma unroll
        for (int nt = 0; nt < 4; ++nt) {
            h8f bf = sB[kc * 4 + nt][L];
            accR[nt] = __builtin_amdgcn_mfma_f32_16x16x32_f16(aR, bf, accR[nt], 0, 0, 0);
            accI[nt] = __builtin_amdgcn_mfma_f32_16x16x32_f16(aI, bf, accI[nt], 0, 0, 0);
        }
    }

    const int colw = L & 15;
    const int rbase = (L >> 4) << 2;
#pragma unroll
    for (int nt = 0; nt < 4; ++nt) {
        const float b = bias[nt * 16 + colw];
#pragma unroll
        for (int rr = 0; rr < 4; ++rr) {
            const int row = band + rbase + rr;
            __builtin_nontemporal_store(accR[nt][rr] + b,
                                        &out[(size_t)row * 64 + nt * 16 + colw]);
            __builtin_nontemporal_store(accI[nt][rr] + b,
                                        &out[(size_t)(N_NODES + row) * 64 + nt * 16 + colw]);
        }
    }
}

// ================= Fallback kernels (small-ws paths) =================
template <int NK>
__global__ __launch_bounds__(256) void xw_kernel(const float* __restrict__ Xr,
                                                 const float* __restrict__ Xi,
                                                 const float* __restrict__ W,
                                                 __half2* __restrict__ XWh) {
    __shared__ float sW[NK][64][64];
    __shared__ float4 sX4[2][32][16];
    const int tid = threadIdx.x;

    float4* swf = (float4*)&sW[0][0][0];
    const float4* gW = (const float4*)W;
    for (int i = tid; i < NK * 1024; i += 256) swf[i] = gW[i];

    const int rowbase = blockIdx.x * 32;
    float4* sxf = (float4*)sX4;
    const float4* gXr = (const float4*)(Xr + (size_t)rowbase * CH);
    const float4* gXi = (const float4*)(Xi + (size_t)rowbase * CH);
    for (int i = tid; i < 512; i += 256) {
        sxf[i] = gXr[i];
        sxf[512 + i] = gXi[i];
    }
    __syncthreads();

    const int col = tid & 63;
    const int rg = tid >> 6;

    float acc[8][2 * NK];
#pragma unroll
    for (int i = 0; i < 8; ++i)
#pragma unroll
        for (int c2 = 0; c2 < 2 * NK; ++c2) acc[i][c2] = 0.0f;

#pragma unroll 2
    for (int j4 = 0; j4 < 16; ++j4) {
        float w[NK][4];
#pragma unroll
        for (int k = 0; k < NK; ++k)
#pragma unroll
            for (int jj = 0; jj < 4; ++jj) w[k][jj] = sW[k][j4 * 4 + jj][col];
#pragma unroll
        for (int i = 0; i < 8; ++i) {
            float4 xr = sX4[0][rg * 8 + i][j4];
            float4 xi = sX4[1][rg * 8 + i][j4];
            const float xra[4] = {xr.x, xr.y, xr.z, xr.w};
            const float xia[4] = {xi.x, xi.y, xi.z, xi.w};
#pragma unroll
            for (int jj = 0; jj < 4; ++jj)
#pragma unroll
                for (int k = 0; k < NK; ++k) {
                    acc[i][2 * k] += xra[jj] * w[k][jj];
                    acc[i][2 * k + 1] += xia[jj] * w[k][jj];
                }
        }
    }

#pragma unroll
    for (int i = 0; i < 8; ++i) {
        __half2* dst = XWh + (size_t)(rowbase + rg * 8 + i) * (NK * 64);
#pragma unroll
        for (int k = 0; k < NK; ++k)
            dst[k * 64 + col] = __floats2half2_rn(acc[i][2 * k], acc[i][2 * k + 1]);
    }
}

template <int NK>
__global__ __launch_bounds__(256) void edge_kernel(const int* __restrict__ rows,
                                                   const int* __restrict__ cols,
                                                   const float* __restrict__ Lr,
                                                   const float* __restrict__ Li,
                                                   const __half2* __restrict__ XWh,
                                                   float* __restrict__ out) {
    const int gid = blockIdx.x * 256 + threadIdx.x;
    const int e = gid >> 6;
    const int lane = gid & 63;
    if (e >= E_EDGES) return;

    const int row = rows[e];
    const int colN = cols[e];
    const __half2* xw = XWh + (size_t)colN * (NK * 64);

    float rc = 0.0f, ic = 0.0f;
#pragma unroll
    for (int k = 0; k < NK; ++k) {
        const float lr = Lr[(size_t)k * E_EDGES + e];
        const float li = Li[(size_t)k * E_EDGES + e];
        float2 v = __half22float2(xw[k * 64 + lane]);
        rc += lr * v.x - li * v.y;
        ic += li * v.x + lr * v.y;
    }
    unsafeAtomicAdd(out + (size_t)row * 64 + lane, rc);
    unsafeAtomicAdd(out + ((size_t)N_NODES + row) * 64 + lane, ic);
}

extern "C" void kernel_launch(void* const* d_in, const int* in_sizes, int n_in,
                              void* d_out, int out_size, void* d_ws, size_t ws_size,
                              hipStream_t stream) {
    const float* Xr = (const float*)d_in[0];
    const float* Xi = (const float*)d_in[1];
    const int* ei = (const int*)d_in[2];
    const float* Lr = (const float*)d_in[3];
    const float* Li = (const float*)d_in[4];
    const float* W = (const float*)d_in[5];
    const float* bias = (const float*)d_in[6];
    float* out = (float*)d_out;

    const int* rows = ei;
    const int* cols = ei + E_EDGES;

    char* wsb = (char*)d_ws;
    const int e_grid = E_EDGES / 256;                             // 6250
    const int edge_grid = (int)((size_t)E_EDGES * 64 / 256);      // 400000
    const int gemm_grid = N_NODES / 32;                           // 3125

    // Main-path ws layout
    unsigned* Xh = (unsigned*)wsb;                                //  25,600,000 B
    __half* Yre = (__half*)(wsb + 25600000);                      //  38,400,000 B
    __half* Yim = (__half*)(wsb + 64000000);                      //  38,400,000 B
    unsigned* payload = (unsigned*)(wsb + 102400000);             //  51,200,000 B (32 B/edge)
    int* counts = (int*)(wsb + 153600000);                        //     400,384 B
    int* rowst = (int*)(wsb + 154000384);                         //     400,384 B
    int* cursor = (int*)(wsb + 154400768);                        //     400,384 B
    int* btot = (int*)(wsb + 154801152);                          //       2,048 B
    const size_t need_new = 154803200;

    if (ws_size >= need_new) {
        xh_zero_kernel<<<6250, 256, 0, stream>>>(Xr, Xi, Xh, counts);
        hist_kernel<<<e_grid, 256, 0, stream>>>(rows, counts);
        scan_a_kernel<<<NBLK, 256, 0, stream>>>(counts, rowst, btot);
        scan_b_kernel<<<1, 512, 0, stream>>>(btot);
        scan_c_kernel<<<NBLK, 256, 0, stream>>>(btot, rowst, cursor);
        scatter_kernel<<<e_grid, 256, 0, stream>>>(rows, cols, Lr, Li, cursor, payload);
        row5_kernel<<<(N_NODES + 3) / 4, 256, 0, stream>>>(rowst, (const uint4*)payload,
                                                           Xh, Yre, Yim);
        yw3_kernel<<<(N_NODES + 63) / 64, 256, 0, stream>>>(Yre, Yim, W, bias, out);
        return;
    }

    // Fallback ws layout (atomic edge scatter over XWh table)
    __half2* XWh = (__half2*)wsb;                                 //  76,800,000 B
    const size_t need_onepass = 76800000;

    if (ws_size >= need_onepass) {
        init_out_kernel<<<2 * N_NODES * CH / 256, 256, 0, stream>>>(bias, out);
        xw_kernel<3><<<gemm_grid, 256, 0, stream>>>(Xr, Xi, W, XWh);
        edge_kernel<3><<<edge_grid, 256, 0, stream>>>(rows, cols, Lr, Li, XWh, out);
    } else {
        init_out_kernel<<<2 * N_NODES * CH / 256, 256, 0, stream>>>(bias, out);
        for (int k = 0; k < 3; ++k) {
            xw_kernel<1><<<gemm_grid, 256, 0, stream>>>(Xr, Xi, W + (size_t)k * 4096, XWh);
            edge_kernel<1><<<edge_grid, 256, 0, stream>>>(rows, cols,
                                                          Lr + (size_t)k * E_EDGES,
                                                          Li + (size_t)k * E_EDGES, XWh, out);
        }
    }
}

// Round 13
// 242.830 us; speedup vs baseline: 1.7619x; 1.2962x over previous
//
#include <hip/hip_runtime.h>
#include <hip/hip_fp16.h>

// SDConv on MI355X.
// Reference: out = sum_k spmm(L_k, X) @ W_k + bias  (complex).
// Structure: apply W AFTER the spmm (k-expansion lives in the L domain), so the
// gather table is just X: 25.6 MB fp16 -> L2/L3-resident.
//   1. xh_zero_kernel: Xh[node][ch] = half2(Xr, Xi); zero coarse-bucket counters.
//   2. Hierarchical CSR build (random-64B-line writeback amplification measured in
//      R9/R10/R12: every random store costs a full line; fix = two-level partition):
//      chist (coarse bucket hist, bucket=row>>8) -> cscan (391-entry scan) ->
//      partA (LDS-binned burst writes of 32 B pre-swizzled records into coarse
//      regions of temp) -> partB (per-bucket LDS per-row sort; random writes
//      confined to the bucket's ~131 KB window -> L2-absorbed; also emits rowst).
//   3. row5_kernel: one wave per row; wave-uniform payload walk (scalar pipe);
//      2 edges/iter, 6-slot payload pipeline, 4 gathers in flight; 6 dot2/edge.
//      Writes Y planar f16: Yre[n][192], Yim[n][192].
//   4. yw3_kernel: out = [Yre;Yim] @ W + bias via v_mfma_f32_16x16x32_f16.

constexpr int N_NODES = 100000;
constexpr int E_EDGES = 1600000;
constexpr int CH = 64;
constexpr int NP = 100096;          // N padded to multiple of 256
constexpr int NBUCK = NP / 256;     // 391 coarse buckets (256 rows each)
constexpr int CHUNK_A = 8192;       // edges per partition block
constexpr int NBLK_A = (E_EDGES + CHUNK_A - 1) / CHUNK_A;   // 196

typedef unsigned u32x4 __attribute__((ext_vector_type(4)));
typedef _Float16 h2f __attribute__((ext_vector_type(2)));
typedef _Float16 h8f __attribute__((ext_vector_type(8)));
typedef float f32x4 __attribute__((ext_vector_type(4)));

// f32 += dot(half2, half2) with f32 accumulation (v_dot2_f32_f16).
__device__ __forceinline__ float fdot2h(unsigned a, unsigned b, float c) {
#if __has_builtin(__builtin_amdgcn_fdot2)
    return __builtin_amdgcn_fdot2(__builtin_bit_cast(h2f, a),
                                  __builtin_bit_cast(h2f, b), c, false);
#else
    float2 af = __half22float2(__builtin_bit_cast(__half2, a));
    float2 bf = __half22float2(__builtin_bit_cast(__half2, b));
    return c + af.x * bf.x + af.y * bf.y;
#endif
}

__device__ __forceinline__ unsigned pack2(float a, float b) {
    return __builtin_bit_cast(unsigned, __floats2half2_rn(a, b));
}

__global__ __launch_bounds__(256) void init_out_kernel(const float* __restrict__ bias,
                                                       float* __restrict__ out) {
    int i = blockIdx.x * 256 + threadIdx.x;
    out[i] = bias[i & 63];
}

// ---------------- Phase 1: Xh = half2(Xr, Xi), [N][64]; zero bucket counters ----------------
__global__ __launch_bounds__(256) void xh_zero_kernel(const float* __restrict__ Xr,
                                                      const float* __restrict__ Xi,
                                                      unsigned* __restrict__ Xh,
                                                      int* __restrict__ bcnt) {
    int i = blockIdx.x * 256 + threadIdx.x;   // grid = N*64/4/256 = 6250 exact
    if (i < NBUCK) bcnt[i] = 0;
    const float4 r = ((const float4*)Xr)[i];
    const float4 m = ((const float4*)Xi)[i];
    uint4 u;
    u.x = pack2(r.x, m.x);
    u.y = pack2(r.y, m.y);
    u.z = pack2(r.z, m.z);
    u.w = pack2(r.w, m.w);
    ((uint4*)Xh)[i] = u;
}

// ---------------- Coarse bucket histogram ----------------
__global__ __launch_bounds__(256) void chist_kernel(const int* __restrict__ rows,
                                                    int* __restrict__ bcnt) {
    __shared__ int lh[NBUCK];
    const int tid = threadIdx.x;
    for (int t = tid; t < NBUCK; t += 256) lh[t] = 0;
    __syncthreads();
    const int base = blockIdx.x * CHUNK_A;
    for (int j = tid; j < CHUNK_A; j += 256) {
        const int e = base + j;
        if (e < E_EDGES) atomicAdd(&lh[rows[e] >> 8], 1);
    }
    __syncthreads();
    for (int t = tid; t < NBUCK; t += 256)
        if (lh[t]) atomicAdd(&bcnt[t], lh[t]);
}

// ---------------- Scan of 391 bucket counts (single block) ----------------
__global__ __launch_bounds__(512) void cscan_kernel(const int* __restrict__ bcnt,
                                                    int* __restrict__ cofs,
                                                    int* __restrict__ ccur) {
    __shared__ int s[512];
    const int t = threadIdx.x;
    int v = (t < NBUCK) ? bcnt[t] : 0;
    s[t] = v;
    __syncthreads();
    for (int off = 1; off < 512; off <<= 1) {
        int a = (t >= off) ? s[t - off] : 0;
        __syncthreads();
        s[t] += a;
        __syncthreads();
    }
    if (t < NBUCK) {
        cofs[t] = s[t] - v;
        ccur[t] = s[t] - v;
    }
    if (t == NBUCK - 1) cofs[NBUCK] = s[t];   // == E_EDGES
}

// ---------------- Phase A: coarse partition, burst writes of 32 B records ----------------
// record: {col, (lr0,-li0), (li0,lr0), (lr1,-li1)} {(li1,lr1), (lr2,-li2), (li2,lr2), row&255}
__global__ __launch_bounds__(256) void partA_kernel(const int* __restrict__ rows,
                                                    const int* __restrict__ cols,
                                                    const float* __restrict__ Lr,
                                                    const float* __restrict__ Li,
                                                    int* __restrict__ ccur,
                                                    u32x4* __restrict__ temp) {
    __shared__ int lh[NBUCK];
    __shared__ int lcur[NBUCK];
    const int tid = threadIdx.x;
    for (int t = tid; t < NBUCK; t += 256) lh[t] = 0;
    __syncthreads();
    const int base = blockIdx.x * CHUNK_A;
    for (int j = tid; j < CHUNK_A; j += 256) {
        const int e = base + j;
        if (e < E_EDGES) atomicAdd(&lh[rows[e] >> 8], 1);
    }
    __syncthreads();
    for (int t = tid; t < NBUCK; t += 256) {
        const int c = lh[t];
        lcur[t] = c ? atomicAdd(&ccur[t], c) : 0;    // one global atomic per (block,bucket)
    }
    __syncthreads();
    for (int j = tid; j < CHUNK_A; j += 256) {
        const int e = base + j;
        if (e >= E_EDGES) continue;
        const int r = rows[e];
        const int pos = atomicAdd(&lcur[r >> 8], 1);
        const float lr0 = Lr[e], li0 = Li[e];
        const float lr1 = Lr[E_EDGES + e], li1 = Li[E_EDGES + e];
        const float lr2 = Lr[2 * E_EDGES + e], li2 = Li[2 * E_EDGES + e];
        u32x4 u0, u1;
        u0.x = (unsigned)cols[e];
        u0.y = pack2(lr0, -li0);
        u0.z = pack2(li0, lr0);
        u0.w = pack2(lr1, -li1);
        u1.x = pack2(li1, lr1);
        u1.y = pack2(lr2, -li2);
        u1.z = pack2(li2, lr2);
        u1.w = (unsigned)(r & 255);
        temp[2 * (size_t)pos] = u0;        // burst-local: lines fully covered
        temp[2 * (size_t)pos + 1] = u1;
    }
}

// ---------------- Phase B: per-bucket fine sort (L2-local) + rowst emit ----------------
__global__ __launch_bounds__(256) void partB_kernel(const int* __restrict__ cofs,
                                                    const u32x4* __restrict__ temp,
                                                    u32x4* __restrict__ payload,
                                                    int* __restrict__ rowst) {
    const int b = blockIdx.x;                 // grid = NBUCK
    const int t = threadIdx.x;
    const int start = cofs[b];
    const int endp = cofs[b + 1];
    __shared__ int lh[256];
    __shared__ int s[256];
    lh[t] = 0;
    __syncthreads();
    for (int i = start + t; i < endp; i += 256)
        atomicAdd(&lh[temp[2 * (size_t)i + 1].w], 1);
    __syncthreads();
    const int v = lh[t];
    s[t] = v;
    __syncthreads();
    for (int off = 1; off < 256; off <<= 1) {
        int a = (t >= off) ? s[t - off] : 0;
        __syncthreads();
        s[t] += a;
        __syncthreads();
    }
    const int excl = s[t] - v;
    rowst[b * 256 + t] = start + excl;
    if (b == NBUCK - 1 && t == 0) rowst[NBUCK * 256] = endp;   // guard
    lh[t] = excl;                              // becomes per-row cursor
    __syncthreads();
    for (int i = start + t; i < endp; i += 256) {
        u32x4 q0 = temp[2 * (size_t)i];
        u32x4 q1 = temp[2 * (size_t)i + 1];
        const int rl = (int)q1.w;
        q1.w = 0u;
        const int pos = start + atomicAdd(&lh[rl], 1);   // random within ~131 KB -> L2
        payload[2 * (size_t)pos] = q0;
        payload[2 * (size_t)pos + 1] = q1;
    }
}

// ---------------- Main pass: one wave per row, 2 edges/iter, 4 gathers in flight ----------------
__global__ __launch_bounds__(256) void row5_kernel(const int* __restrict__ rowst,
                                                   const uint4* __restrict__ payload,
                                                   const unsigned* __restrict__ Xh,
                                                   __half* __restrict__ Yre,
                                                   __half* __restrict__ Yim) {
    // Wave-uniform row index: payload addresses provably uniform -> scalar pipe.
    const int r = __builtin_amdgcn_readfirstlane(blockIdx.x * 4 + ((int)threadIdx.x >> 6));
    const int lane = threadIdx.x & 63;
    if (r >= N_NODES) return;
    const int start = rowst[r];
    const int end = rowst[r + 1];
    const int n = end - start;

    float aR0 = 0.f, aI0 = 0.f, aR1 = 0.f, aI1 = 0.f, aR2 = 0.f, aI2 = 0.f;

    auto gx = [&](unsigned col) -> unsigned { return Xh[(size_t)col * 64 + lane]; };
    auto accum = [&](const uint4& q0, const uint4& q1, unsigned xv) {
        aR0 = fdot2h(q0.y, xv, aR0);
        aI0 = fdot2h(q0.z, xv, aI0);
        aR1 = fdot2h(q0.w, xv, aR1);
        aI1 = fdot2h(q1.x, xv, aI1);
        aR2 = fdot2h(q1.y, xv, aR2);
        aI2 = fdot2h(q1.z, xv, aI2);
    };

    if (n >= 8) {
        int p = start;
        uint4 A0 = payload[2 * (size_t)p], A1 = payload[2 * (size_t)p + 1];
        uint4 B0 = payload[2 * (size_t)(p + 1)], B1 = payload[2 * (size_t)(p + 1) + 1];
        uint4 C0 = payload[2 * (size_t)(p + 2)], C1 = payload[2 * (size_t)(p + 2) + 1];
        uint4 D0 = payload[2 * (size_t)(p + 3)], D1 = payload[2 * (size_t)(p + 3) + 1];
        uint4 E0 = payload[2 * (size_t)(p + 4)], E1 = payload[2 * (size_t)(p + 4) + 1];
        uint4 F0 = payload[2 * (size_t)(p + 5)], F1 = payload[2 * (size_t)(p + 5) + 1];
        unsigned xA = gx(A0.x), xB = gx(B0.x), xC = gx(C0.x), xD = gx(D0.x);

        for (; p + 7 < end; p += 2) {
            uint4 G0 = payload[2 * (size_t)(p + 6)], G1 = payload[2 * (size_t)(p + 6) + 1];
            uint4 H0 = payload[2 * (size_t)(p + 7)], H1 = payload[2 * (size_t)(p + 7) + 1];
            unsigned xE = gx(E0.x);
            unsigned xF = gx(F0.x);
            accum(A0, A1, xA);
            accum(B0, B1, xB);
            A0 = C0; A1 = C1; xA = xC;
            B0 = D0; B1 = D1; xB = xD;
            C0 = E0; C1 = E1; xC = xE;
            D0 = F0; D1 = F1; xD = xF;
            E0 = G0; E1 = G1;
            F0 = H0; F1 = H1;
        }
        accum(A0, A1, xA);
        accum(B0, B1, xB);
        accum(C0, C1, xC);
        accum(D0, D1, xD);
        unsigned xE = gx(E0.x);
        unsigned xF = gx(F0.x);
        accum(E0, E1, xE);
        accum(F0, F1, xF);
        if (p + 6 < end) {
            uint4 G0 = payload[2 * (size_t)(p + 6)], G1 = payload[2 * (size_t)(p + 6) + 1];
            unsigned xG = gx(G0.x);
            accum(G0, G1, xG);
        }
    } else {
        for (int p = start; p < end; ++p) {
            uint4 q0 = payload[2 * (size_t)p], q1 = payload[2 * (size_t)p + 1];
            unsigned xv = gx(q0.x);
            accum(q0, q1, xv);
        }
    }

    __half* yr = Yre + (size_t)r * 192;
    __half* yi = Yim + (size_t)r * 192;
    yr[lane] = __float2half(aR0);
    yr[64 + lane] = __float2half(aR1);
    yr[128 + lane] = __float2half(aR2);
    yi[lane] = __float2half(aI0);
    yi[64 + lane] = __float2half(aI1);
    yi[128 + lane] = __float2half(aI2);
}

// ---------------- Phase 4: out = [Yre;Yim] @ Wcat + bias via MFMA ----------------
__global__ __launch_bounds__(256) void yw3_kernel(const __half* __restrict__ Yre,
                                                  const __half* __restrict__ Yim,
                                                  const float* __restrict__ W,
                                                  const float* __restrict__ bias,
                                                  float* __restrict__ out) {
    __shared__ h8f sB[24][64];   // pre-packed B frags, 24 KB
    const int tid = threadIdx.x;

    for (int s = tid; s < 24 * 64; s += 256) {
        const int L = s & 63;
        const int ntkc = s >> 6;
        const int nt = ntkc & 3;
        const int kc = ntkc >> 2;
        const int colb = nt * 16 + (L & 15);
        const int kbase = kc * 32 + ((L >> 4) << 3);
        h8f v;
#pragma unroll
        for (int j = 0; j < 8; ++j) v[j] = (_Float16)W[(kbase + j) * 64 + colb];
        sB[ntkc][L] = v;
    }
    __syncthreads();

    const int wv = tid >> 6;
    const int L = tid & 63;
    const int band = blockIdx.x * 64 + wv * 16;
    if (band >= N_NODES) return;

    const int m = L & 15;
    const int ko = (L >> 4) << 3;
    const int rowA = band + m;

    f32x4 accR[4], accI[4];
#pragma unroll
    for (int nt = 0; nt < 4; ++nt) {
        accR[nt] = (f32x4){0.f, 0.f, 0.f, 0.f};
        accI[nt] = (f32x4){0.f, 0.f, 0.f, 0.f};
    }

#pragma unroll
    for (int kc = 0; kc < 6; ++kc) {
        h8f aR = *(const h8f*)(Yre + (size_t)rowA * 192 + kc * 32 + ko);
        h8f aI = *(const h8f*)(Yim + (size_t)rowA * 192 + kc * 32 + ko);
#pragma unroll
        for (int nt = 0; nt < 4; ++nt) {
            h8f bf = sB[kc * 4 + nt][L];
            accR[nt] = __builtin_amdgcn_mfma_f32_16x16x32_f16(aR, bf, accR[nt], 0, 0, 0);
            accI[nt] = __builtin_amdgcn_mfma_f32_16x16x32_f16(aI, bf, accI[nt], 0, 0, 0);
        }
    }

    const int colw = L & 15;
    const int rbase = (L >> 4) << 2;
#pragma unroll
    for (int nt = 0; nt < 4; ++nt) {
        const float b = bias[nt * 16 + colw];
#pragma unroll
        for (int rr = 0; rr < 4; ++rr) {
            const int row = band + rbase + rr;
            __builtin_nontemporal_store(accR[nt][rr] + b,
                                        &out[(size_t)row * 64 + nt * 16 + colw]);
            __builtin_nontemporal_store(accI[nt][rr] + b,
                                        &out[(size_t)(N_NODES + row) * 64 + nt * 16 + colw]);
        }
    }
}

// ================= Fallback kernels (small-ws paths) =================
template <int NK>
__global__ __launch_bounds__(256) void xw_kernel(const float* __restrict__ Xr,
                                                 const float* __restrict__ Xi,
                                                 const float* __restrict__ W,
                                                 __half2* __restrict__ XWh) {
    __shared__ float sW[NK][64][64];
    __shared__ float4 sX4[2][32][16];
    const int tid = threadIdx.x;

    float4* swf = (float4*)&sW[0][0][0];
    const float4* gW = (const float4*)W;
    for (int i = tid; i < NK * 1024; i += 256) swf[i] = gW[i];

    const int rowbase = blockIdx.x * 32;
    float4* sxf = (float4*)sX4;
    const float4* gXr = (const float4*)(Xr + (size_t)rowbase * CH);
    const float4* gXi = (const float4*)(Xi + (size_t)rowbase * CH);
    for (int i = tid; i < 512; i += 256) {
        sxf[i] = gXr[i];
        sxf[512 + i] = gXi[i];
    }
    __syncthreads();

    const int col = tid & 63;
    const int rg = tid >> 6;

    float acc[8][2 * NK];
#pragma unroll
    for (int i = 0; i < 8; ++i)
#pragma unroll
        for (int c2 = 0; c2 < 2 * NK; ++c2) acc[i][c2] = 0.0f;

#pragma unroll 2
    for (int j4 = 0; j4 < 16; ++j4) {
        float w[NK][4];
#pragma unroll
        for (int k = 0; k < NK; ++k)
#pragma unroll
            for (int jj = 0; jj < 4; ++jj) w[k][jj] = sW[k][j4 * 4 + jj][col];
#pragma unroll
        for (int i = 0; i < 8; ++i) {
            float4 xr = sX4[0][rg * 8 + i][j4];
            float4 xi = sX4[1][rg * 8 + i][j4];
            const float xra[4] = {xr.x, xr.y, xr.z, xr.w};
            const float xia[4] = {xi.x, xi.y, xi.z, xi.w};
#pragma unroll
            for (int jj = 0; jj < 4; ++jj)
#pragma unroll
                for (int k = 0; k < NK; ++k) {
                    acc[i][2 * k] += xra[jj] * w[k][jj];
                    acc[i][2 * k + 1] += xia[jj] * w[k][jj];
                }
        }
    }

#pragma unroll
    for (int i = 0; i < 8; ++i) {
        __half2* dst = XWh + (size_t)(rowbase + rg * 8 + i) * (NK * 64);
#pragma unroll
        for (int k = 0; k < NK; ++k)
            dst[k * 64 + col] = __floats2half2_rn(acc[i][2 * k], acc[i][2 * k + 1]);
    }
}

template <int NK>
__global__ __launch_bounds__(256) void edge_kernel(const int* __restrict__ rows,
                                                   const int* __restrict__ cols,
                                                   const float* __restrict__ Lr,
                                                   const float* __restrict__ Li,
                                                   const __half2* __restrict__ XWh,
                                                   float* __restrict__ out) {
    const int gid = blockIdx.x * 256 + threadIdx.x;
    const int e = gid >> 6;
    const int lane = gid & 63;
    if (e >= E_EDGES) return;

    const int row = rows[e];
    const int colN = cols[e];
    const __half2* xw = XWh + (size_t)colN * (NK * 64);

    float rc = 0.0f, ic = 0.0f;
#pragma unroll
    for (int k = 0; k < NK; ++k) {
        const float lr = Lr[(size_t)k * E_EDGES + e];
        const float li = Li[(size_t)k * E_EDGES + e];
        float2 v = __half22float2(xw[k * 64 + lane]);
        rc += lr * v.x - li * v.y;
        ic += li * v.x + lr * v.y;
    }
    unsafeAtomicAdd(out + (size_t)row * 64 + lane, rc);
    unsafeAtomicAdd(out + ((size_t)N_NODES + row) * 64 + lane, ic);
}

extern "C" void kernel_launch(void* const* d_in, const int* in_sizes, int n_in,
                              void* d_out, int out_size, void* d_ws, size_t ws_size,
                              hipStream_t stream) {
    const float* Xr = (const float*)d_in[0];
    const float* Xi = (const float*)d_in[1];
    const int* ei = (const int*)d_in[2];
    const float* Lr = (const float*)d_in[3];
    const float* Li = (const float*)d_in[4];
    const float* W = (const float*)d_in[5];
    const float* bias = (const float*)d_in[6];
    float* out = (float*)d_out;

    const int* rows = ei;
    const int* cols = ei + E_EDGES;

    char* wsb = (char*)d_ws;
    const int edge_grid = (int)((size_t)E_EDGES * 64 / 256);      // 400000
    const int gemm_grid = N_NODES / 32;                           // 3125

    // Main-path ws layout
    unsigned* Xh = (unsigned*)wsb;                                //  25,600,000 B
    __half* Yre = (__half*)(wsb + 25600000);                      //  38,400,000 B
    __half* Yim = (__half*)(wsb + 64000000);                      //  38,400,000 B
    unsigned* payload = (unsigned*)(wsb + 102400000);             //  51,200,000 B (32 B/edge)
    u32x4* temp = (u32x4*)(wsb + 153600000);                      //  51,200,000 B
    int* rowst = (int*)(wsb + 204800000);                         //     404,480 B (NP+1 used)
    int* bcnt = (int*)(wsb + 205204480);                          //       1,600 B
    int* cofs = (int*)(wsb + 205206080);                          //       1,600 B
    int* ccur = (int*)(wsb + 205207680);                          //       1,600 B
    const size_t need_new = 205209280;

    if (ws_size >= need_new) {
        xh_zero_kernel<<<6250, 256, 0, stream>>>(Xr, Xi, Xh, bcnt);
        chist_kernel<<<NBLK_A, 256, 0, stream>>>(rows, bcnt);
        cscan_kernel<<<1, 512, 0, stream>>>(bcnt, cofs, ccur);
        partA_kernel<<<NBLK_A, 256, 0, stream>>>(rows, cols, Lr, Li, ccur, temp);
        partB_kernel<<<NBUCK, 256, 0, stream>>>(cofs, temp, (u32x4*)payload, rowst);
        row5_kernel<<<(N_NODES + 3) / 4, 256, 0, stream>>>(rowst, (const uint4*)payload,
                                                           Xh, Yre, Yim);
        yw3_kernel<<<(N_NODES + 63) / 64, 256, 0, stream>>>(Yre, Yim, W, bias, out);
        return;
    }

    // Fallback ws layout (atomic edge scatter over XWh table)
    __half2* XWh = (__half2*)wsb;                                 //  76,800,000 B
    const size_t need_onepass = 76800000;

    if (ws_size >= need_onepass) {
        init_out_kernel<<<2 * N_NODES * CH / 256, 256, 0, stream>>>(bias, out);
        xw_kernel<3><<<gemm_grid, 256, 0, stream>>>(Xr, Xi, W, XWh);
        edge_kernel<3><<<edge_grid, 256, 0, stream>>>(rows, cols, Lr, Li, XWh, out);
    } else {
        init_out_kernel<<<2 * N_NODES * CH / 256, 256, 0, stream>>>(bias, out);
        for (int k = 0; k < 3; ++k) {
            xw_kernel<1><<<gemm_grid, 256, 0, stream>>>(Xr, Xi, W + (size_t)k * 4096, XWh);
            edge_kernel<1><<<edge_grid, 256, 0, stream>>>(rows, cols,
                                                          Lr + (size_t)k * E_EDGES,
                                                          Li + (size_t)k * E_EDGES, XWh, out);
        }
    }
}

// Round 14
// 223.273 us; speedup vs baseline: 1.9163x; 1.0876x over previous
//
#include <hip/hip_runtime.h>
#include <hip/hip_fp16.h>

// SDConv on MI355X.
// Reference: out = sum_k spmm(L_k, X) @ W_k + bias  (complex).
// Structure: apply W AFTER the spmm (k-expansion lives in the L domain), so the
// gather table is just X: 25.6 MB fp16 -> L2/L3-resident.
//   1. xh_zero_kernel: Xh[node][ch] = half2(Xr, Xi); zero coarse-bucket counters.
//   2. Hierarchical CSR build (random-64B-line writeback amplification measured in
//      R9/R10/R12; fix = two-level partition). R13 lesson: partition kernels were
//      occupancy-starved (196 blocks = 7%); now 1024-thread blocks, CHUNK=4096
//      -> 391 blocks x 16 waves (~76% occupancy).
//      chist -> cscan -> partA (LDS-binned burst writes, 32 B records) ->
//      partB (per-bucket fine sort in its ~131 KB window -> L2-absorbed; emits rowst).
//   3. row5_kernel: one wave per row; wave-uniform payload walk (scalar pipe);
//      2 edges/iter, 6-slot payload pipeline, 4 gathers in flight; 6 dot2/edge.
//   4. yw3_kernel: out = [Yre;Yim] @ W + bias via v_mfma_f32_16x16x32_f16.

constexpr int N_NODES = 100000;
constexpr int E_EDGES = 1600000;
constexpr int CH = 64;
constexpr int NP = 100096;          // N padded to multiple of 256
constexpr int NBUCK = NP / 256;     // 391 coarse buckets (256 rows each)
constexpr int CHUNK_A = 4096;       // edges per partition block
constexpr int NBLK_A = (E_EDGES + CHUNK_A - 1) / CHUNK_A;   // 391

typedef unsigned u32x4 __attribute__((ext_vector_type(4)));
typedef _Float16 h2f __attribute__((ext_vector_type(2)));
typedef _Float16 h8f __attribute__((ext_vector_type(8)));
typedef float f32x4 __attribute__((ext_vector_type(4)));

// f32 += dot(half2, half2) with f32 accumulation (v_dot2_f32_f16).
__device__ __forceinline__ float fdot2h(unsigned a, unsigned b, float c) {
#if __has_builtin(__builtin_amdgcn_fdot2)
    return __builtin_amdgcn_fdot2(__builtin_bit_cast(h2f, a),
                                  __builtin_bit_cast(h2f, b), c, false);
#else
    float2 af = __half22float2(__builtin_bit_cast(__half2, a));
    float2 bf = __half22float2(__builtin_bit_cast(__half2, b));
    return c + af.x * bf.x + af.y * bf.y;
#endif
}

__device__ __forceinline__ unsigned pack2(float a, float b) {
    return __builtin_bit_cast(unsigned, __floats2half2_rn(a, b));
}

__global__ __launch_bounds__(256) void init_out_kernel(const float* __restrict__ bias,
                                                       float* __restrict__ out) {
    int i = blockIdx.x * 256 + threadIdx.x;
    out[i] = bias[i & 63];
}

// ---------------- Phase 1: Xh = half2(Xr, Xi), [N][64]; zero bucket counters ----------------
__global__ __launch_bounds__(256) void xh_zero_kernel(const float* __restrict__ Xr,
                                                      const float* __restrict__ Xi,
                                                      unsigned* __restrict__ Xh,
                                                      int* __restrict__ bcnt) {
    int i = blockIdx.x * 256 + threadIdx.x;   // grid = N*64/4/256 = 6250 exact
    if (i < NBUCK) bcnt[i] = 0;
    const float4 r = ((const float4*)Xr)[i];
    const float4 m = ((const float4*)Xi)[i];
    uint4 u;
    u.x = pack2(r.x, m.x);
    u.y = pack2(r.y, m.y);
    u.z = pack2(r.z, m.z);
    u.w = pack2(r.w, m.w);
    ((uint4*)Xh)[i] = u;
}

// ---------------- Coarse bucket histogram (1024-thread blocks) ----------------
__global__ __launch_bounds__(1024) void chist_kernel(const int* __restrict__ rows,
                                                     int* __restrict__ bcnt) {
    __shared__ int lh[NBUCK];
    const int tid = threadIdx.x;
    for (int t = tid; t < NBUCK; t += 1024) lh[t] = 0;
    __syncthreads();
    const int base = blockIdx.x * CHUNK_A;
    for (int j = tid; j < CHUNK_A; j += 1024) {
        const int e = base + j;
        if (e < E_EDGES) atomicAdd(&lh[rows[e] >> 8], 1);
    }
    __syncthreads();
    for (int t = tid; t < NBUCK; t += 1024)
        if (lh[t]) atomicAdd(&bcnt[t], lh[t]);
}

// ---------------- Scan of 391 bucket counts (single block) ----------------
__global__ __launch_bounds__(512) void cscan_kernel(const int* __restrict__ bcnt,
                                                    int* __restrict__ cofs,
                                                    int* __restrict__ ccur) {
    __shared__ int s[512];
    const int t = threadIdx.x;
    int v = (t < NBUCK) ? bcnt[t] : 0;
    s[t] = v;
    __syncthreads();
    for (int off = 1; off < 512; off <<= 1) {
        int a = (t >= off) ? s[t - off] : 0;
        __syncthreads();
        s[t] += a;
        __syncthreads();
    }
    if (t < NBUCK) {
        cofs[t] = s[t] - v;
        ccur[t] = s[t] - v;
    }
    if (t == NBUCK - 1) cofs[NBUCK] = s[t];   // == E_EDGES
}

// ---------------- Phase A: coarse partition, burst writes of 32 B records ----------------
// record: {col, (lr0,-li0), (li0,lr0), (lr1,-li1)} {(li1,lr1), (lr2,-li2), (li2,lr2), row&255}
__global__ __launch_bounds__(1024) void partA_kernel(const int* __restrict__ rows,
                                                     const int* __restrict__ cols,
                                                     const float* __restrict__ Lr,
                                                     const float* __restrict__ Li,
                                                     int* __restrict__ ccur,
                                                     u32x4* __restrict__ temp) {
    __shared__ int lh[NBUCK];
    __shared__ int lcur[NBUCK];
    const int tid = threadIdx.x;
    for (int t = tid; t < NBUCK; t += 1024) lh[t] = 0;
    __syncthreads();
    const int base = blockIdx.x * CHUNK_A;
    for (int j = tid; j < CHUNK_A; j += 1024) {
        const int e = base + j;
        if (e < E_EDGES) atomicAdd(&lh[rows[e] >> 8], 1);
    }
    __syncthreads();
    for (int t = tid; t < NBUCK; t += 1024) {
        const int c = lh[t];
        lcur[t] = c ? atomicAdd(&ccur[t], c) : 0;    // one global atomic per (block,bucket)
    }
    __syncthreads();
    for (int j = tid; j < CHUNK_A; j += 1024) {
        const int e = base + j;
        if (e >= E_EDGES) continue;
        const int r = rows[e];
        const int pos = atomicAdd(&lcur[r >> 8], 1);
        const float lr0 = Lr[e], li0 = Li[e];
        const float lr1 = Lr[E_EDGES + e], li1 = Li[E_EDGES + e];
        const float lr2 = Lr[2 * E_EDGES + e], li2 = Li[2 * E_EDGES + e];
        u32x4 u0, u1;
        u0.x = (unsigned)cols[e];
        u0.y = pack2(lr0, -li0);
        u0.z = pack2(li0, lr0);
        u0.w = pack2(lr1, -li1);
        u1.x = pack2(li1, lr1);
        u1.y = pack2(lr2, -li2);
        u1.z = pack2(li2, lr2);
        u1.w = (unsigned)(r & 255);
        temp[2 * (size_t)pos] = u0;        // burst-local: lines mostly covered
        temp[2 * (size_t)pos + 1] = u1;
    }
}

// ---------------- Phase B: per-bucket fine sort (L2-local) + rowst emit ----------------
__global__ __launch_bounds__(256) void partB_kernel(const int* __restrict__ cofs,
                                                    const u32x4* __restrict__ temp,
                                                    u32x4* __restrict__ payload,
                                                    int* __restrict__ rowst) {
    const int b = blockIdx.x;                 // grid = NBUCK
    const int t = threadIdx.x;
    const int start = cofs[b];
    const int endp = cofs[b + 1];
    __shared__ int lh[256];
    __shared__ int s[256];
    lh[t] = 0;
    __syncthreads();
    for (int i = start + t; i < endp; i += 256)
        atomicAdd(&lh[temp[2 * (size_t)i + 1].w], 1);
    __syncthreads();
    const int v = lh[t];
    s[t] = v;
    __syncthreads();
    for (int off = 1; off < 256; off <<= 1) {
        int a = (t >= off) ? s[t - off] : 0;
        __syncthreads();
        s[t] += a;
        __syncthreads();
    }
    const int excl = s[t] - v;
    rowst[b * 256 + t] = start + excl;
    if (b == NBUCK - 1 && t == 0) rowst[NBUCK * 256] = endp;   // guard
    lh[t] = excl;                              // becomes per-row cursor
    __syncthreads();
    for (int i = start + t; i < endp; i += 256) {
        u32x4 q0 = temp[2 * (size_t)i];
        u32x4 q1 = temp[2 * (size_t)i + 1];
        const int rl = (int)q1.w;
        q1.w = 0u;
        const int pos = start + atomicAdd(&lh[rl], 1);   // random within ~131 KB -> L2
        payload[2 * (size_t)pos] = q0;
        payload[2 * (size_t)pos + 1] = q1;
    }
}

// ---------------- Main pass: one wave per row, 2 edges/iter, 4 gathers in flight ----------------
__global__ __launch_bounds__(256) void row5_kernel(const int* __restrict__ rowst,
                                                   const uint4* __restrict__ payload,
                                                   const unsigned* __restrict__ Xh,
                                                   __half* __restrict__ Yre,
                                                   __half* __restrict__ Yim) {
    // Wave-uniform row index: payload addresses provably uniform -> scalar pipe.
    const int r = __builtin_amdgcn_readfirstlane(blockIdx.x * 4 + ((int)threadIdx.x >> 6));
    const int lane = threadIdx.x & 63;
    if (r >= N_NODES) return;
    const int start = rowst[r];
    const int end = rowst[r + 1];
    const int n = end - start;

    float aR0 = 0.f, aI0 = 0.f, aR1 = 0.f, aI1 = 0.f, aR2 = 0.f, aI2 = 0.f;

    auto gx = [&](unsigned col) -> unsigned { return Xh[(size_t)col * 64 + lane]; };
    auto accum = [&](const uint4& q0, const uint4& q1, unsigned xv) {
        aR0 = fdot2h(q0.y, xv, aR0);
        aI0 = fdot2h(q0.z, xv, aI0);
        aR1 = fdot2h(q0.w, xv, aR1);
        aI1 = fdot2h(q1.x, xv, aI1);
        aR2 = fdot2h(q1.y, xv, aR2);
        aI2 = fdot2h(q1.z, xv, aI2);
    };

    if (n >= 8) {
        int p = start;
        uint4 A0 = payload[2 * (size_t)p], A1 = payload[2 * (size_t)p + 1];
        uint4 B0 = payload[2 * (size_t)(p + 1)], B1 = payload[2 * (size_t)(p + 1) + 1];
        uint4 C0 = payload[2 * (size_t)(p + 2)], C1 = payload[2 * (size_t)(p + 2) + 1];
        uint4 D0 = payload[2 * (size_t)(p + 3)], D1 = payload[2 * (size_t)(p + 3) + 1];
        uint4 E0 = payload[2 * (size_t)(p + 4)], E1 = payload[2 * (size_t)(p + 4) + 1];
        uint4 F0 = payload[2 * (size_t)(p + 5)], F1 = payload[2 * (size_t)(p + 5) + 1];
        unsigned xA = gx(A0.x), xB = gx(B0.x), xC = gx(C0.x), xD = gx(D0.x);

        for (; p + 7 < end; p += 2) {
            uint4 G0 = payload[2 * (size_t)(p + 6)], G1 = payload[2 * (size_t)(p + 6) + 1];
            uint4 H0 = payload[2 * (size_t)(p + 7)], H1 = payload[2 * (size_t)(p + 7) + 1];
            unsigned xE = gx(E0.x);
            unsigned xF = gx(F0.x);
            accum(A0, A1, xA);
            accum(B0, B1, xB);
            A0 = C0; A1 = C1; xA = xC;
            B0 = D0; B1 = D1; xB = xD;
            C0 = E0; C1 = E1; xC = xE;
            D0 = F0; D1 = F1; xD = xF;
            E0 = G0; E1 = G1;
            F0 = H0; F1 = H1;
        }
        accum(A0, A1, xA);
        accum(B0, B1, xB);
        accum(C0, C1, xC);
        accum(D0, D1, xD);
        unsigned xE = gx(E0.x);
        unsigned xF = gx(F0.x);
        accum(E0, E1, xE);
        accum(F0, F1, xF);
        if (p + 6 < end) {
            uint4 G0 = payload[2 * (size_t)(p + 6)], G1 = payload[2 * (size_t)(p + 6) + 1];
            unsigned xG = gx(G0.x);
            accum(G0, G1, xG);
        }
    } else {
        for (int p = start; p < end; ++p) {
            uint4 q0 = payload[2 * (size_t)p], q1 = payload[2 * (size_t)p + 1];
            unsigned xv = gx(q0.x);
            accum(q0, q1, xv);
        }
    }

    __half* yr = Yre + (size_t)r * 192;
    __half* yi = Yim + (size_t)r * 192;
    yr[lane] = __float2half(aR0);
    yr[64 + lane] = __float2half(aR1);
    yr[128 + lane] = __float2half(aR2);
    yi[lane] = __float2half(aI0);
    yi[64 + lane] = __float2half(aI1);
    yi[128 + lane] = __float2half(aI2);
}

// ---------------- Phase 4: out = [Yre;Yim] @ Wcat + bias via MFMA ----------------
__global__ __launch_bounds__(256) void yw3_kernel(const __half* __restrict__ Yre,
                                                  const __half* __restrict__ Yim,
                                                  const float* __restrict__ W,
                                                  const float* __restrict__ bias,
                                                  float* __restrict__ out) {
    __shared__ h8f sB[24][64];   // pre-packed B frags, 24 KB
    const int tid = threadIdx.x;

    for (int s = tid; s < 24 * 64; s += 256) {
        const int L = s & 63;
        const int ntkc = s >> 6;
        const int nt = ntkc & 3;
        const int kc = ntkc >> 2;
        const int colb = nt * 16 + (L & 15);
        const int kbase = kc * 32 + ((L >> 4) << 3);
        h8f v;
#pragma unroll
        for (int j = 0; j < 8; ++j) v[j] = (_Float16)W[(kbase + j) * 64 + colb];
        sB[ntkc][L] = v;
    }
    __syncthreads();

    const int wv = tid >> 6;
    const int L = tid & 63;
    const int band = blockIdx.x * 64 + wv * 16;
    if (band >= N_NODES) return;

    const int m = L & 15;
    const int ko = (L >> 4) << 3;
    const int rowA = band + m;

    f32x4 accR[4], accI[4];
#pragma unroll
    for (int nt = 0; nt < 4; ++nt) {
        accR[nt] = (f32x4){0.f, 0.f, 0.f, 0.f};
        accI[nt] = (f32x4){0.f, 0.f, 0.f, 0.f};
    }

#pragma unroll
    for (int kc = 0; kc < 6; ++kc) {
        h8f aR = *(const h8f*)(Yre + (size_t)rowA * 192 + kc * 32 + ko);
        h8f aI = *(const h8f*)(Yim + (size_t)rowA * 192 + kc * 32 + ko);
#pragma unroll
        for (int nt = 0; nt < 4; ++nt) {
            h8f bf = sB[kc * 4 + nt][L];
            accR[nt] = __builtin_amdgcn_mfma_f32_16x16x32_f16(aR, bf, accR[nt], 0, 0, 0);
            accI[nt] = __builtin_amdgcn_mfma_f32_16x16x32_f16(aI, bf, accI[nt], 0, 0, 0);
        }
    }

    const int colw = L & 15;
    const int rbase = (L >> 4) << 2;
#pragma unroll
    for (int nt = 0; nt < 4; ++nt) {
        const float b = bias[nt * 16 + colw];
#pragma unroll
        for (int rr = 0; rr < 4; ++rr) {
            const int row = band + rbase + rr;
            __builtin_nontemporal_store(accR[nt][rr] + b,
                                        &out[(size_t)row * 64 + nt * 16 + colw]);
            __builtin_nontemporal_store(accI[nt][rr] + b,
                                        &out[(size_t)(N_NODES + row) * 64 + nt * 16 + colw]);
        }
    }
}

// ================= Fallback kernels (small-ws paths) =================
template <int NK>
__global__ __launch_bounds__(256) void xw_kernel(const float* __restrict__ Xr,
                                                 const float* __restrict__ Xi,
                                                 const float* __restrict__ W,
                                                 __half2* __restrict__ XWh) {
    __shared__ float sW[NK][64][64];
    __shared__ float4 sX4[2][32][16];
    const int tid = threadIdx.x;

    float4* swf = (float4*)&sW[0][0][0];
    const float4* gW = (const float4*)W;
    for (int i = tid; i < NK * 1024; i += 256) swf[i] = gW[i];

    const int rowbase = blockIdx.x * 32;
    float4* sxf = (float4*)sX4;
    const float4* gXr = (const float4*)(Xr + (size_t)rowbase * CH);
    const float4* gXi = (const float4*)(Xi + (size_t)rowbase * CH);
    for (int i = tid; i < 512; i += 256) {
        sxf[i] = gXr[i];
        sxf[512 + i] = gXi[i];
    }
    __syncthreads();

    const int col = tid & 63;
    const int rg = tid >> 6;

    float acc[8][2 * NK];
#pragma unroll
    for (int i = 0; i < 8; ++i)
#pragma unroll
        for (int c2 = 0; c2 < 2 * NK; ++c2) acc[i][c2] = 0.0f;

#pragma unroll 2
    for (int j4 = 0; j4 < 16; ++j4) {
        float w[NK][4];
#pragma unroll
        for (int k = 0; k < NK; ++k)
#pragma unroll
            for (int jj = 0; jj < 4; ++jj) w[k][jj] = sW[k][j4 * 4 + jj][col];
#pragma unroll
        for (int i = 0; i < 8; ++i) {
            float4 xr = sX4[0][rg * 8 + i][j4];
            float4 xi = sX4[1][rg * 8 + i][j4];
            const float xra[4] = {xr.x, xr.y, xr.z, xr.w};
            const float xia[4] = {xi.x, xi.y, xi.z, xi.w};
#pragma unroll
            for (int jj = 0; jj < 4; ++jj)
#pragma unroll
                for (int k = 0; k < NK; ++k) {
                    acc[i][2 * k] += xra[jj] * w[k][jj];
                    acc[i][2 * k + 1] += xia[jj] * w[k][jj];
                }
        }
    }

#pragma unroll
    for (int i = 0; i < 8; ++i) {
        __half2* dst = XWh + (size_t)(rowbase + rg * 8 + i) * (NK * 64);
#pragma unroll
        for (int k = 0; k < NK; ++k)
            dst[k * 64 + col] = __floats2half2_rn(acc[i][2 * k], acc[i][2 * k + 1]);
    }
}

template <int NK>
__global__ __launch_bounds__(256) void edge_kernel(const int* __restrict__ rows,
                                                   const int* __restrict__ cols,
                                                   const float* __restrict__ Lr,
                                                   const float* __restrict__ Li,
                                                   const __half2* __restrict__ XWh,
                                                   float* __restrict__ out) {
    const int gid = blockIdx.x * 256 + threadIdx.x;
    const int e = gid >> 6;
    const int lane = gid & 63;
    if (e >= E_EDGES) return;

    const int row = rows[e];
    const int colN = cols[e];
    const __half2* xw = XWh + (size_t)colN * (NK * 64);

    float rc = 0.0f, ic = 0.0f;
#pragma unroll
    for (int k = 0; k < NK; ++k) {
        const float lr = Lr[(size_t)k * E_EDGES + e];
        const float li = Li[(size_t)k * E_EDGES + e];
        float2 v = __half22float2(xw[k * 64 + lane]);
        rc += lr * v.x - li * v.y;
        ic += li * v.x + lr * v.y;
    }
    unsafeAtomicAdd(out + (size_t)row * 64 + lane, rc);
    unsafeAtomicAdd(out + ((size_t)N_NODES + row) * 64 + lane, ic);
}

extern "C" void kernel_launch(void* const* d_in, const int* in_sizes, int n_in,
                              void* d_out, int out_size, void* d_ws, size_t ws_size,
                              hipStream_t stream) {
    const float* Xr = (const float*)d_in[0];
    const float* Xi = (const float*)d_in[1];
    const int* ei = (const int*)d_in[2];
    const float* Lr = (const float*)d_in[3];
    const float* Li = (const float*)d_in[4];
    const float* W = (const float*)d_in[5];
    const float* bias = (const float*)d_in[6];
    float* out = (float*)d_out;

    const int* rows = ei;
    const int* cols = ei + E_EDGES;

    char* wsb = (char*)d_ws;
    const int edge_grid = (int)((size_t)E_EDGES * 64 / 256);      // 400000
    const int gemm_grid = N_NODES / 32;                           // 3125

    // Main-path ws layout
    unsigned* Xh = (unsigned*)wsb;                                //  25,600,000 B
    __half* Yre = (__half*)(wsb + 25600000);                      //  38,400,000 B
    __half* Yim = (__half*)(wsb + 64000000);                      //  38,400,000 B
    unsigned* payload = (unsigned*)(wsb + 102400000);             //  51,200,000 B (32 B/edge)
    u32x4* temp = (u32x4*)(wsb + 153600000);                      //  51,200,000 B
    int* rowst = (int*)(wsb + 204800000);                         //     404,480 B (NP+1 used)
    int* bcnt = (int*)(wsb + 205204480);                          //       1,600 B
    int* cofs = (int*)(wsb + 205206080);                          //       1,600 B
    int* ccur = (int*)(wsb + 205207680);                          //       1,600 B
    const size_t need_new = 205209280;

    if (ws_size >= need_new) {
        xh_zero_kernel<<<6250, 256, 0, stream>>>(Xr, Xi, Xh, bcnt);
        chist_kernel<<<NBLK_A, 1024, 0, stream>>>(rows, bcnt);
        cscan_kernel<<<1, 512, 0, stream>>>(bcnt, cofs, ccur);
        partA_kernel<<<NBLK_A, 1024, 0, stream>>>(rows, cols, Lr, Li, ccur, temp);
        partB_kernel<<<NBUCK, 256, 0, stream>>>(cofs, temp, (u32x4*)payload, rowst);
        row5_kernel<<<(N_NODES + 3) / 4, 256, 0, stream>>>(rowst, (const uint4*)payload,
                                                           Xh, Yre, Yim);
        yw3_kernel<<<(N_NODES + 63) / 64, 256, 0, stream>>>(Yre, Yim, W, bias, out);
        return;
    }

    // Fallback ws layout (atomic edge scatter over XWh table)
    __half2* XWh = (__half2*)wsb;                                 //  76,800,000 B
    const size_t need_onepass = 76800000;

    if (ws_size >= need_onepass) {
        init_out_kernel<<<2 * N_NODES * CH / 256, 256, 0, stream>>>(bias, out);
        xw_kernel<3><<<gemm_grid, 256, 0, stream>>>(Xr, Xi, W, XWh);
        edge_kernel<3><<<edge_grid, 256, 0, stream>>>(rows, cols, Lr, Li, XWh, out);
    } else {
        init_out_kernel<<<2 * N_NODES * CH / 256, 256, 0, stream>>>(bias, out);
        for (int k = 0; k < 3; ++k) {
            xw_kernel<1><<<gemm_grid, 256, 0, stream>>>(Xr, Xi, W + (size_t)k * 4096, XWh);
            edge_kernel<1><<<edge_grid, 256, 0, stream>>>(rows, cols,
                                                          Lr + (size_t)k * E_EDGES,
                                                          Li + (size_t)k * E_EDGES, XWh, out);
        }
    }
}

// Round 15
// 209.366 us; speedup vs baseline: 2.0435x; 1.0664x over previous
//
#include <hip/hip_runtime.h>
#include <hip/hip_fp16.h>

// SDConv on MI355X.
// Reference: out = sum_k spmm(L_k, X) @ W_k + bias  (complex).
// Structure: apply W AFTER the spmm (k-expansion lives in the L domain), so the
// gather table is just X: 25.6 MB fp16 -> L2/L3-resident.
//   1. xh_zero_kernel: Xh[node][ch] = half2(Xr, Xi); zero coarse-bucket counters.
//   2. Hierarchical CSR build (random-64B-line writeback amplification measured
//      R9/R10/R12; occupancy lesson R13): chist -> cscan -> partA (burst writes of
//      32 B pre-swizzled records) -> partB (per-bucket fine sort, L2-local; rowst).
//   3. row6_kernel (FUSED row pass + output GEMM): block = 16 rows; 4 waves x 4 rows
//      each, 6-slot payload pipeline / 4 gathers in flight, 6 dot2/edge; Y goes to
//      LDS (12.8 KB, 400 B row pitch) instead of global (kills the 154 MB Y round
//      trip of R14); barrier; each wave MFMAs its 16-col quadrant (A from LDS,
//      B from pre-packed Bpack) and NT-stores out + bias.
//   4. pack_kernel: one-time pack of W into MFMA B-fragment layout (24 KB).

constexpr int N_NODES = 100000;
constexpr int E_EDGES = 1600000;
constexpr int CH = 64;
constexpr int NP = 100096;          // N padded to multiple of 256
constexpr int NBUCK = NP / 256;     // 391 coarse buckets (256 rows each)
constexpr int CHUNK_A = 4096;       // edges per partition block
constexpr int NBLK_A = (E_EDGES + CHUNK_A - 1) / CHUNK_A;   // 391

typedef unsigned u32x4 __attribute__((ext_vector_type(4)));
typedef _Float16 h2f __attribute__((ext_vector_type(2)));
typedef _Float16 h8f __attribute__((ext_vector_type(8)));
typedef float f32x4 __attribute__((ext_vector_type(4)));

// f32 += dot(half2, half2) with f32 accumulation (v_dot2_f32_f16).
__device__ __forceinline__ float fdot2h(unsigned a, unsigned b, float c) {
#if __has_builtin(__builtin_amdgcn_fdot2)
    return __builtin_amdgcn_fdot2(__builtin_bit_cast(h2f, a),
                                  __builtin_bit_cast(h2f, b), c, false);
#else
    float2 af = __half22float2(__builtin_bit_cast(__half2, a));
    float2 bf = __half22float2(__builtin_bit_cast(__half2, b));
    return c + af.x * bf.x + af.y * bf.y;
#endif
}

__device__ __forceinline__ unsigned pack2(float a, float b) {
    return __builtin_bit_cast(unsigned, __floats2half2_rn(a, b));
}

__global__ __launch_bounds__(256) void init_out_kernel(const float* __restrict__ bias,
                                                       float* __restrict__ out) {
    int i = blockIdx.x * 256 + threadIdx.x;
    out[i] = bias[i & 63];
}

// ---------------- Phase 1: Xh = half2(Xr, Xi), [N][64]; zero bucket counters ----------------
__global__ __launch_bounds__(256) void xh_zero_kernel(const float* __restrict__ Xr,
                                                      const float* __restrict__ Xi,
                                                      unsigned* __restrict__ Xh,
                                                      int* __restrict__ bcnt) {
    int i = blockIdx.x * 256 + threadIdx.x;   // grid = N*64/4/256 = 6250 exact
    if (i < NBUCK) bcnt[i] = 0;
    const float4 r = ((const float4*)Xr)[i];
    const float4 m = ((const float4*)Xi)[i];
    uint4 u;
    u.x = pack2(r.x, m.x);
    u.y = pack2(r.y, m.y);
    u.z = pack2(r.z, m.z);
    u.w = pack2(r.w, m.w);
    ((uint4*)Xh)[i] = u;
}

// ---------------- W -> MFMA B-fragment pack (once, 24 KB) ----------------
// Bpack[(kc*4+nt)*64 + L] = 8 halves: W[kc*32 + (L>>4)*8 + j][nt*16 + (L&15)]
__global__ __launch_bounds__(256) void pack_kernel(const float* __restrict__ W,
                                                   h8f* __restrict__ Bpack) {
    for (int s = threadIdx.x; s < 24 * 64; s += 256) {
        const int L = s & 63;
        const int ntkc = s >> 6;
        const int nt = ntkc & 3;
        const int kc = ntkc >> 2;
        const int colb = nt * 16 + (L & 15);
        const int kbase = kc * 32 + ((L >> 4) << 3);
        h8f v;
#pragma unroll
        for (int j = 0; j < 8; ++j) v[j] = (_Float16)W[(kbase + j) * 64 + colb];
        Bpack[s] = v;
    }
}

// ---------------- Coarse bucket histogram (1024-thread blocks) ----------------
__global__ __launch_bounds__(1024) void chist_kernel(const int* __restrict__ rows,
                                                     int* __restrict__ bcnt) {
    __shared__ int lh[NBUCK];
    const int tid = threadIdx.x;
    for (int t = tid; t < NBUCK; t += 1024) lh[t] = 0;
    __syncthreads();
    const int base = blockIdx.x * CHUNK_A;
    for (int j = tid; j < CHUNK_A; j += 1024) {
        const int e = base + j;
        if (e < E_EDGES) atomicAdd(&lh[rows[e] >> 8], 1);
    }
    __syncthreads();
    for (int t = tid; t < NBUCK; t += 1024)
        if (lh[t]) atomicAdd(&bcnt[t], lh[t]);
}

// ---------------- Scan of 391 bucket counts (single block) ----------------
__global__ __launch_bounds__(512) void cscan_kernel(const int* __restrict__ bcnt,
                                                    int* __restrict__ cofs,
                                                    int* __restrict__ ccur) {
    __shared__ int s[512];
    const int t = threadIdx.x;
    int v = (t < NBUCK) ? bcnt[t] : 0;
    s[t] = v;
    __syncthreads();
    for (int off = 1; off < 512; off <<= 1) {
        int a = (t >= off) ? s[t - off] : 0;
        __syncthreads();
        s[t] += a;
        __syncthreads();
    }
    if (t < NBUCK) {
        cofs[t] = s[t] - v;
        ccur[t] = s[t] - v;
    }
    if (t == NBUCK - 1) cofs[NBUCK] = s[t];   // == E_EDGES
}

// ---------------- Phase A: coarse partition, burst writes of 32 B records ----------------
// record: {col, (lr0,-li0), (li0,lr0), (lr1,-li1)} {(li1,lr1), (lr2,-li2), (li2,lr2), row&255}
__global__ __launch_bounds__(1024) void partA_kernel(const int* __restrict__ rows,
                                                     const int* __restrict__ cols,
                                                     const float* __restrict__ Lr,
                                                     const float* __restrict__ Li,
                                                     int* __restrict__ ccur,
                                                     u32x4* __restrict__ temp) {
    __shared__ int lh[NBUCK];
    __shared__ int lcur[NBUCK];
    const int tid = threadIdx.x;
    for (int t = tid; t < NBUCK; t += 1024) lh[t] = 0;
    __syncthreads();
    const int base = blockIdx.x * CHUNK_A;
    for (int j = tid; j < CHUNK_A; j += 1024) {
        const int e = base + j;
        if (e < E_EDGES) atomicAdd(&lh[rows[e] >> 8], 1);
    }
    __syncthreads();
    for (int t = tid; t < NBUCK; t += 1024) {
        const int c = lh[t];
        lcur[t] = c ? atomicAdd(&ccur[t], c) : 0;    // one global atomic per (block,bucket)
    }
    __syncthreads();
    for (int j = tid; j < CHUNK_A; j += 1024) {
        const int e = base + j;
        if (e >= E_EDGES) continue;
        const int r = rows[e];
        const int pos = atomicAdd(&lcur[r >> 8], 1);
        const float lr0 = Lr[e], li0 = Li[e];
        const float lr1 = Lr[E_EDGES + e], li1 = Li[E_EDGES + e];
        const float lr2 = Lr[2 * E_EDGES + e], li2 = Li[2 * E_EDGES + e];
        u32x4 u0, u1;
        u0.x = (unsigned)cols[e];
        u0.y = pack2(lr0, -li0);
        u0.z = pack2(li0, lr0);
        u0.w = pack2(lr1, -li1);
        u1.x = pack2(li1, lr1);
        u1.y = pack2(lr2, -li2);
        u1.z = pack2(li2, lr2);
        u1.w = (unsigned)(r & 255);
        temp[2 * (size_t)pos] = u0;        // burst-local: lines mostly covered
        temp[2 * (size_t)pos + 1] = u1;
    }
}

// ---------------- Phase B: per-bucket fine sort (L2-local) + rowst emit ----------------
__global__ __launch_bounds__(256) void partB_kernel(const int* __restrict__ cofs,
                                                    const u32x4* __restrict__ temp,
                                                    u32x4* __restrict__ payload,
                                                    int* __restrict__ rowst) {
    const int b = blockIdx.x;                 // grid = NBUCK
    const int t = threadIdx.x;
    const int start = cofs[b];
    const int endp = cofs[b + 1];
    __shared__ int lh[256];
    __shared__ int s[256];
    lh[t] = 0;
    __syncthreads();
    for (int i = start + t; i < endp; i += 256) {
        u32x4 q1 = __builtin_nontemporal_load(temp + 2 * (size_t)i + 1);
        atomicAdd(&lh[q1.w], 1);
    }
    __syncthreads();
    const int v = lh[t];
    s[t] = v;
    __syncthreads();
    for (int off = 1; off < 256; off <<= 1) {
        int a = (t >= off) ? s[t - off] : 0;
        __syncthreads();
        s[t] += a;
        __syncthreads();
    }
    const int excl = s[t] - v;
    rowst[b * 256 + t] = start + excl;
    if (b == NBUCK - 1 && t == 0) rowst[NBUCK * 256] = endp;   // guard
    lh[t] = excl;                              // becomes per-row cursor
    __syncthreads();
    for (int i = start + t; i < endp; i += 256) {
        u32x4 q0 = __builtin_nontemporal_load(temp + 2 * (size_t)i);
        u32x4 q1 = __builtin_nontemporal_load(temp + 2 * (size_t)i + 1);
        const int rl = (int)q1.w;
        q1.w = 0u;
        const int pos = start + atomicAdd(&lh[rl], 1);   // random within ~131 KB -> L2
        payload[2 * (size_t)pos] = q0;
        payload[2 * (size_t)pos + 1] = q1;
    }
}

// ---------------- FUSED main pass: 16 rows/block; edge phase + MFMA epilogue ----------------
__global__ __launch_bounds__(256) void row6_kernel(const int* __restrict__ rowst,
                                                   const uint4* __restrict__ payload,
                                                   const unsigned* __restrict__ Xh,
                                                   const h8f* __restrict__ Bpack,
                                                   const float* __restrict__ bias,
                                                   float* __restrict__ out) {
    __shared__ __half sY[2][16][200];          // 400 B row pitch: 2-way LDS alias only
    const int w = (int)threadIdx.x >> 6;       // wave id = 4 rows / nt quadrant
    const int lane = threadIdx.x & 63;
    const int band = blockIdx.x * 16;          // grid = 6250 exact

    for (int q = 0; q < 4; ++q) {
        const int ri = w * 4 + q;
        const int r = __builtin_amdgcn_readfirstlane(band + ri);
        const int start = rowst[r];
        const int end = rowst[r + 1];
        const int n = end - start;

        float aR0 = 0.f, aI0 = 0.f, aR1 = 0.f, aI1 = 0.f, aR2 = 0.f, aI2 = 0.f;

        auto gx = [&](unsigned col) -> unsigned { return Xh[(size_t)col * 64 + lane]; };
        auto accum = [&](const uint4& q0, const uint4& q1, unsigned xv) {
            aR0 = fdot2h(q0.y, xv, aR0);
            aI0 = fdot2h(q0.z, xv, aI0);
            aR1 = fdot2h(q0.w, xv, aR1);
            aI1 = fdot2h(q1.x, xv, aI1);
            aR2 = fdot2h(q1.y, xv, aR2);
            aI2 = fdot2h(q1.z, xv, aI2);
        };

        if (n >= 8) {
            int p = start;
            uint4 A0 = payload[2 * (size_t)p], A1 = payload[2 * (size_t)p + 1];
            uint4 B0 = payload[2 * (size_t)(p + 1)], B1 = payload[2 * (size_t)(p + 1) + 1];
            uint4 C0 = payload[2 * (size_t)(p + 2)], C1 = payload[2 * (size_t)(p + 2) + 1];
            uint4 D0 = payload[2 * (size_t)(p + 3)], D1 = payload[2 * (size_t)(p + 3) + 1];
            uint4 E0 = payload[2 * (size_t)(p + 4)], E1 = payload[2 * (size_t)(p + 4) + 1];
            uint4 F0 = payload[2 * (size_t)(p + 5)], F1 = payload[2 * (size_t)(p + 5) + 1];
            unsigned xA = gx(A0.x), xB = gx(B0.x), xC = gx(C0.x), xD = gx(D0.x);

            for (; p + 7 < end; p += 2) {
                uint4 G0 = payload[2 * (size_t)(p + 6)], G1 = payload[2 * (size_t)(p + 6) + 1];
                uint4 H0 = payload[2 * (size_t)(p + 7)], H1 = payload[2 * (size_t)(p + 7) + 1];
                unsigned xE = gx(E0.x);
                unsigned xF = gx(F0.x);
                accum(A0, A1, xA);
                accum(B0, B1, xB);
                A0 = C0; A1 = C1; xA = xC;
                B0 = D0; B1 = D1; xB = xD;
                C0 = E0; C1 = E1; xC = xE;
                D0 = F0; D1 = F1; xD = xF;
                E0 = G0; E1 = G1;
                F0 = H0; F1 = H1;
            }
            accum(A0, A1, xA);
            accum(B0, B1, xB);
            accum(C0, C1, xC);
            accum(D0, D1, xD);
            unsigned xE = gx(E0.x);
            unsigned xF = gx(F0.x);
            accum(E0, E1, xE);
            accum(F0, F1, xF);
            if (p + 6 < end) {
                uint4 G0 = payload[2 * (size_t)(p + 6)], G1 = payload[2 * (size_t)(p + 6) + 1];
                unsigned xG = gx(G0.x);
                accum(G0, G1, xG);
            }
        } else {
            for (int p = start; p < end; ++p) {
                uint4 q0 = payload[2 * (size_t)p], q1 = payload[2 * (size_t)p + 1];
                unsigned xv = gx(q0.x);
                accum(q0, q1, xv);
            }
        }

        sY[0][ri][lane] = __float2half(aR0);
        sY[0][ri][64 + lane] = __float2half(aR1);
        sY[0][ri][128 + lane] = __float2half(aR2);
        sY[1][ri][lane] = __float2half(aI0);
        sY[1][ri][64 + lane] = __float2half(aI1);
        sY[1][ri][128 + lane] = __float2half(aI2);
    }
    __syncthreads();

    // MFMA epilogue: wave w = column quadrant nt = w.
    const int nt = w;
    const int m = lane & 15;
    const int ko = (lane >> 4) << 3;
    f32x4 accR = (f32x4){0.f, 0.f, 0.f, 0.f};
    f32x4 accI = (f32x4){0.f, 0.f, 0.f, 0.f};
#pragma unroll
    for (int kc = 0; kc < 6; ++kc) {
        h8f bf = Bpack[(kc * 4 + nt) * 64 + lane];                    // L3-hot, 16 B/lane
        h8f aR = *(const h8f*)&sY[0][m][kc * 32 + ko];
        h8f aI = *(const h8f*)&sY[1][m][kc * 32 + ko];
        accR = __builtin_amdgcn_mfma_f32_16x16x32_f16(aR, bf, accR, 0, 0, 0);
        accI = __builtin_amdgcn_mfma_f32_16x16x32_f16(aI, bf, accI, 0, 0, 0);
    }
    const int colw = lane & 15;
    const int rbase = (lane >> 4) << 2;
    const float b = bias[nt * 16 + colw];
#pragma unroll
    for (int rr = 0; rr < 4; ++rr) {
        const int row = band + rbase + rr;
        __builtin_nontemporal_store(accR[rr] + b,
                                    &out[(size_t)row * 64 + nt * 16 + colw]);
        __builtin_nontemporal_store(accI[rr] + b,
                                    &out[(size_t)(N_NODES + row) * 64 + nt * 16 + colw]);
    }
}

// ================= Fallback kernels (small-ws paths) =================
template <int NK>
__global__ __launch_bounds__(256) void xw_kernel(const float* __restrict__ Xr,
                                                 const float* __restrict__ Xi,
                                                 const float* __restrict__ W,
                                                 __half2* __restrict__ XWh) {
    __shared__ float sW[NK][64][64];
    __shared__ float4 sX4[2][32][16];
    const int tid = threadIdx.x;

    float4* swf = (float4*)&sW[0][0][0];
    const float4* gW = (const float4*)W;
    for (int i = tid; i < NK * 1024; i += 256) swf[i] = gW[i];

    const int rowbase = blockIdx.x * 32;
    float4* sxf = (float4*)sX4;
    const float4* gXr = (const float4*)(Xr + (size_t)rowbase * CH);
    const float4* gXi = (const float4*)(Xi + (size_t)rowbase * CH);
    for (int i = tid; i < 512; i += 256) {
        sxf[i] = gXr[i];
        sxf[512 + i] = gXi[i];
    }
    __syncthreads();

    const int col = tid & 63;
    const int rg = tid >> 6;

    float acc[8][2 * NK];
#pragma unroll
    for (int i = 0; i < 8; ++i)
#pragma unroll
        for (int c2 = 0; c2 < 2 * NK; ++c2) acc[i][c2] = 0.0f;

#pragma unroll 2
    for (int j4 = 0; j4 < 16; ++j4) {
        float w[NK][4];
#pragma unroll
        for (int k = 0; k < NK; ++k)
#pragma unroll
            for (int jj = 0; jj < 4; ++jj) w[k][jj] = sW[k][j4 * 4 + jj][col];
#pragma unroll
        for (int i = 0; i < 8; ++i) {
            float4 xr = sX4[0][rg * 8 + i][j4];
            float4 xi = sX4[1][rg * 8 + i][j4];
            const float xra[4] = {xr.x, xr.y, xr.z, xr.w};
            const float xia[4] = {xi.x, xi.y, xi.z, xi.w};
#pragma unroll
            for (int jj = 0; jj < 4; ++jj)
#pragma unroll
                for (int k = 0; k < NK; ++k) {
                    acc[i][2 * k] += xra[jj] * w[k][jj];
                    acc[i][2 * k + 1] += xia[jj] * w[k][jj];
                }
        }
    }

#pragma unroll
    for (int i = 0; i < 8; ++i) {
        __half2* dst = XWh + (size_t)(rowbase + rg * 8 + i) * (NK * 64);
#pragma unroll
        for (int k = 0; k < NK; ++k)
            dst[k * 64 + col] = __floats2half2_rn(acc[i][2 * k], acc[i][2 * k + 1]);
    }
}

template <int NK>
__global__ __launch_bounds__(256) void edge_kernel(const int* __restrict__ rows,
                                                   const int* __restrict__ cols,
                                                   const float* __restrict__ Lr,
                                                   const float* __restrict__ Li,
                                                   const __half2* __restrict__ XWh,
                                                   float* __restrict__ out) {
    const int gid = blockIdx.x * 256 + threadIdx.x;
    const int e = gid >> 6;
    const int lane = gid & 63;
    if (e >= E_EDGES) return;

    const int row = rows[e];
    const int colN = cols[e];
    const __half2* xw = XWh + (size_t)colN * (NK * 64);

    float rc = 0.0f, ic = 0.0f;
#pragma unroll
    for (int k = 0; k < NK; ++k) {
        const float lr = Lr[(size_t)k * E_EDGES + e];
        const float li = Li[(size_t)k * E_EDGES + e];
        float2 v = __half22float2(xw[k * 64 + lane]);
        rc += lr * v.x - li * v.y;
        ic += li * v.x + lr * v.y;
    }
    unsafeAtomicAdd(out + (size_t)row * 64 + lane, rc);
    unsafeAtomicAdd(out + ((size_t)N_NODES + row) * 64 + lane, ic);
}

extern "C" void kernel_launch(void* const* d_in, const int* in_sizes, int n_in,
                              void* d_out, int out_size, void* d_ws, size_t ws_size,
                              hipStream_t stream) {
    const float* Xr = (const float*)d_in[0];
    const float* Xi = (const float*)d_in[1];
    const int* ei = (const int*)d_in[2];
    const float* Lr = (const float*)d_in[3];
    const float* Li = (const float*)d_in[4];
    const float* W = (const float*)d_in[5];
    const float* bias = (const float*)d_in[6];
    float* out = (float*)d_out;

    const int* rows = ei;
    const int* cols = ei + E_EDGES;

    char* wsb = (char*)d_ws;
    const int edge_grid = (int)((size_t)E_EDGES * 64 / 256);      // 400000
    const int gemm_grid = N_NODES / 32;                           // 3125

    // Main-path ws layout (Y buffers eliminated by fusion)
    unsigned* Xh = (unsigned*)wsb;                                //  25,600,000 B
    unsigned* payload = (unsigned*)(wsb + 25600000);              //  51,200,000 B (32 B/edge)
    u32x4* temp = (u32x4*)(wsb + 76800000);                       //  51,200,000 B
    int* rowst = (int*)(wsb + 128000000);                         //     404,480 B (NP+1 used)
    int* bcnt = (int*)(wsb + 128404480);                          //       1,600 B
    int* cofs = (int*)(wsb + 128406080);                          //       1,600 B
    int* ccur = (int*)(wsb + 128407680);                          //       1,600 B
    h8f* Bpack = (h8f*)(wsb + 128409280);                         //      24,576 B
    const size_t need_new = 128433856;

    if (ws_size >= need_new) {
        xh_zero_kernel<<<6250, 256, 0, stream>>>(Xr, Xi, Xh, bcnt);
        pack_kernel<<<1, 256, 0, stream>>>(W, Bpack);
        chist_kernel<<<NBLK_A, 1024, 0, stream>>>(rows, bcnt);
        cscan_kernel<<<1, 512, 0, stream>>>(bcnt, cofs, ccur);
        partA_kernel<<<NBLK_A, 1024, 0, stream>>>(rows, cols, Lr, Li, ccur, temp);
        partB_kernel<<<NBUCK, 256, 0, stream>>>(cofs, temp, (u32x4*)payload, rowst);
        row6_kernel<<<N_NODES / 16, 256, 0, stream>>>(rowst, (const uint4*)payload, Xh,
                                                      Bpack, bias, out);
        return;
    }

    // Fallback ws layout (atomic edge scatter over XWh table)
    __half2* XWh = (__half2*)wsb;                                 //  76,800,000 B
    const size_t need_onepass = 76800000;

    if (ws_size >= need_onepass) {
        init_out_kernel<<<2 * N_NODES * CH / 256, 256, 0, stream>>>(bias, out);
        xw_kernel<3><<<gemm_grid, 256, 0, stream>>>(Xr, Xi, W, XWh);
        edge_kernel<3><<<edge_grid, 256, 0, stream>>>(rows, cols, Lr, Li, XWh, out);
    } else {
        init_out_kernel<<<2 * N_NODES * CH / 256, 256, 0, stream>>>(bias, out);
        for (int k = 0; k < 3; ++k) {
            xw_kernel<1><<<gemm_grid, 256, 0, stream>>>(Xr, Xi, W + (size_t)k * 4096, XWh);
            edge_kernel<1><<<edge_grid, 256, 0, stream>>>(rows, cols,
                                                          Lr + (size_t)k * E_EDGES,
                                                          Li + (size_t)k * E_EDGES, XWh, out);
        }
    }
}